// Round 5
// baseline (266.562 us; speedup 1.0000x reference)
//
#include <hip/hip_runtime.h>

#define NNODE 50000
#define NEDGE 1600000
#define SCAN_BLOCKS 196   // ceil(50000/256)
#define NBLOCKS 1024      // 4 blocks/CU
#define NWAVES (NBLOCKS*8)
#define EPW 196           // ceil(NEDGE/NWAVES)

typedef __attribute__((ext_vector_type(8))) _Float16 half8;
typedef __attribute__((ext_vector_type(2))) __fp16 fp16x2;
typedef __attribute__((ext_vector_type(4))) float f32x4;
typedef __attribute__((ext_vector_type(2))) float f32x2;

union H2U { fp16x2 h; unsigned int u; };
union H8U { half8 h8; unsigned int u[4]; };

__device__ __forceinline__ float b2f(unsigned short u) {
    return __uint_as_float(((unsigned int)u) << 16);
}
__device__ __forceinline__ f32x2 lo2(f32x4 v) { f32x2 r; r.x = v[0]; r.y = v[1]; return r; }
__device__ __forceinline__ f32x2 hi2(f32x4 v) { f32x2 r; r.x = v[2]; r.y = v[3]; return r; }

// packed-pair silu -> packed f16 pair
__device__ __forceinline__ unsigned int silu2_pk(f32x2 x) {
    f32x2 u = x * (-1.44269504f);
    f32x2 e;
    e.x = __builtin_amdgcn_exp2f(u.x);
    e.y = __builtin_amdgcn_exp2f(u.y);
    f32x2 d = e + 1.0f;
    f32x2 r;
    r.x = __builtin_amdgcn_rcpf(d.x);
    r.y = __builtin_amdgcn_rcpf(d.y);
    f32x2 s = x * r;
    H2U h2; h2.h = __builtin_amdgcn_cvt_pkrtz(s.x, s.y);
    return h2.u;
}

// channel permutation folding the MFMA D-layout into the next layer's
// B-fragment layout (cols of W1/W2/W3 only; repack restores true space).
__device__ __forceinline__ int dp_pi(int s) {
    return (((s >> 5) & 1) << 5) | (((s >> 2) & 3) << 3)
         | (((s >> 4) & 1) << 2) | (s & 3);
}
__device__ __forceinline__ void repack_silu(const f32x4 acc[4], half8& b0, half8& b1) {
    H8U u0, u1;
    u0.u[0] = silu2_pk(lo2(acc[0])); u0.u[1] = silu2_pk(hi2(acc[0]));
    u0.u[2] = silu2_pk(lo2(acc[1])); u0.u[3] = silu2_pk(hi2(acc[1]));
    u1.u[0] = silu2_pk(lo2(acc[2])); u1.u[1] = silu2_pk(hi2(acc[2]));
    u1.u[2] = silu2_pk(lo2(acc[3])); u1.u[3] = silu2_pk(hi2(acc[3]));
    b0 = u0.h8; b1 = u1.h8;
}

template<bool F32>
__device__ __forceinline__ float ldv(const void* p, int i) {
    return F32 ? ((const float*)p)[i] : b2f(((const unsigned short*)p)[i]);
}

__device__ __forceinline__ int lb_poffs(const int* __restrict__ poffs, int val) {
    int lo = 0, hi = NNODE;
    while (lo < hi) { int mid = (lo + hi) >> 1; if (poffs[mid] < val) lo = mid + 1; else hi = mid; }
    return lo;
}

// ---------------------------------------------------------------------------
// hist (+ input-dtype probe in block 0) + per-edge rank record.
// ---------------------------------------------------------------------------
__global__ void dp_hist(const int* __restrict__ esrc, int* __restrict__ counts,
                        int* __restrict__ rank,
                        const unsigned int* __restrict__ dw, int* __restrict__ flag) {
    if (blockIdx.x == 0 && threadIdx.x < 64) {
        const int lane = threadIdx.x;
        unsigned int w = dw[lane];
        unsigned int hb_ = (w >> 8) & 0xFF;
        bool bf16like = (hb_ == 0x3F) || (hb_ == 0x40);
        unsigned long long m = __ballot(bf16like);
        if (lane == 0) *flag = (__popcll(m) > 32) ? 0 : 1;
    }
    int i = blockIdx.x*256 + threadIdx.x;
    if (i < NEDGE) rank[i] = atomicAdd(&counts[esrc[i]], 1);
}

// s1: per-block unpadded sums
__global__ void dp_s1(const int* __restrict__ counts, int* __restrict__ bsum) {
    int i = blockIdx.x*256 + threadIdx.x;
    int v = (i < NNODE) ? counts[i] : 0;
    #pragma unroll
    for (int o = 32; o > 0; o >>= 1) v += __shfl_down(v, o);
    __shared__ int wsum[4];
    if ((threadIdx.x & 63) == 0) wsum[threadIdx.x >> 6] = v;
    __syncthreads();
    if (threadIdx.x == 0) bsum[blockIdx.x] = wsum[0] + wsum[1] + wsum[2] + wsum[3];
}

__global__ void dp_s2(const int* __restrict__ bsum, int* __restrict__ bpre) {
    __shared__ int sh[256];
    int t = threadIdx.x;
    int v = (t < SCAN_BLOCKS) ? bsum[t] : 0;
    sh[t] = v;
    __syncthreads();
    for (int o = 1; o < 256; o <<= 1) {
        int x = (t >= o) ? sh[t - o] : 0;
        __syncthreads();
        sh[t] += x;
        __syncthreads();
    }
    if (t < SCAN_BLOCKS) bpre[t] = sh[t] - v;
}

__global__ void dp_s3(const int* __restrict__ counts, const int* __restrict__ bpre,
                      int* __restrict__ poffs) {
    __shared__ int sh[256];
    int t = threadIdx.x;
    int i = blockIdx.x*256 + t;
    int c = (i < NNODE) ? counts[i] : 0;
    sh[t] = c;
    __syncthreads();
    for (int o = 1; o < 256; o <<= 1) {
        int x = (t >= o) ? sh[t - o] : 0;
        __syncthreads();
        sh[t] += x;
        __syncthreads();
    }
    int excl = sh[t] - c + bpre[blockIdx.x];
    if (i < NNODE) poffs[i] = excl;
    if (i == NNODE-1) poffs[NNODE] = excl + c;
}

// ---------------------------------------------------------------------------
// Scatter + per-edge prep, atomic-free, DENSE positions. Also computes the
// per-wave node-range starts (wstart).
// ---------------------------------------------------------------------------
template<bool F32>
__device__ __forceinline__ void scat_body(
    const int* __restrict__ esrc, const int* __restrict__ edst,
    const int* __restrict__ species,
    const void* __restrict__ dist, const void* __restrict__ swt,
    const void* __restrict__ vec,
    const int* __restrict__ poffs, const int* __restrict__ rank,
    uint4* __restrict__ srec)
{
    int i = blockIdx.x*256 + threadIdx.x;
    if (i >= NEDGE) return;
    int pe = poffs[esrc[i]] + rank[i];
    float d  = ldv<F32>(dist, i);
    float sw = ldv<F32>(swt, i);
    float inv = 1.0f / d;
    float sij = sw * inv;
    float rx = sij * ldv<F32>(vec, 3*i+0) * inv;
    float ry = sij * ldv<F32>(vec, 3*i+1) * inv;
    float rz = sij * ldv<F32>(vec, 3*i+2) * inv;
    int z = species[edst[i]] & 15;
    uint4 rc;
    rc.x = (__float_as_uint(sij) & ~15u) | (unsigned)z;
    rc.y = __float_as_uint(rx);
    rc.z = __float_as_uint(ry);
    rc.w = __float_as_uint(rz);
    srec[pe] = rc;
}

__global__ void dp_scat(const int* __restrict__ flagp,
                        const int* __restrict__ esrc, const int* __restrict__ edst,
                        const int* __restrict__ species,
                        const void* __restrict__ dist, const void* __restrict__ swt,
                        const void* __restrict__ vec,
                        const int* __restrict__ poffs, const int* __restrict__ rank,
                        uint4* __restrict__ srec, int* __restrict__ wstart)
{
    int i = blockIdx.x*256 + threadIdx.x;
    if (i <= NWAVES) wstart[i] = lb_poffs(poffs, i*EPW);
    if (*flagp) scat_body<true >(esrc, edst, species, dist, swt, vec, poffs, rank, srec);
    else        scat_body<false>(esrc, edst, species, dist, swt, vec, poffs, rank, srec);
}

// ---------------------------------------------------------------------------
// Fused MLP + aggregation + embedding. Node-decoupled group stream.
// This revision (LDS-traffic cut, zero VGPR growth):
//  - L1 as MFMA with LDS-resident pre-permuted W1' fragments (4 b128 reads
//    per paired group instead of 12 random-z table reads; b1 folded via a
//    constant-1 input row k=17; B operand built in registers).
//  - G-hoist: layer-4 G computed once per group; the node-segment walk is
//    pure VALU (mask * R * pk_fma) -- no per-segment W4/MFMA redo.
// Config identical to the 154us baseline: 1024 blocks, 4 blocks/CU.
// ---------------------------------------------------------------------------
struct __align__(16) FusedShared {
    _Float16 WT[3][4096];   // [L][c*64 + (k ^ ((c&7)<<3))]
    _Float16 A1L[2048];     // W1' frags: [c*32 + (k ^ ((c&3)<<3))] = W1row(k)[pi(c)]
    float bD[2][64];        // b2[pi(s)], b3[pi(s)]
    float Rl[8][128];       // per-wave R: A 0..63, B 64..127
    int nb[8][64];          // per-wave node-boundary cache poffs[n_lo+1+j]
};                          // 35328 B -> 4 blocks/CU

__global__ __launch_bounds__(512, 4) void dp_fused(
    const int* __restrict__ flagp,
    const void* __restrict__ W1, const void* __restrict__ b1,
    const void* __restrict__ W2, const void* __restrict__ b2,
    const void* __restrict__ W3, const void* __restrict__ b3,
    const void* __restrict__ W4, const void* __restrict__ b4,
    const int* __restrict__ poffs, const int* __restrict__ wstart,
    const uint4* __restrict__ srec,
    float* __restrict__ out)
{
    __shared__ FusedShared sh;
    const bool F32 = (*flagp != 0);
    const int tid = threadIdx.x;

    for (int i = tid; i < 4096; i += 512) {
        int k = i >> 6, c = i & 63;
        int kk = c*64 + (k ^ ((c & 7) << 3));
        int pc = dp_pi(c);
        if (F32) {
            sh.WT[0][kk] = (_Float16)ldv<true>(W2, k*64 + pc);
            sh.WT[1][kk] = (_Float16)ldv<true>(W3, k*64 + pc);
            sh.WT[2][kk] = (_Float16)ldv<true>(W4, k*64 + c);
        } else {
            sh.WT[0][kk] = (_Float16)ldv<false>(W2, k*64 + pc);
            sh.WT[1][kk] = (_Float16)ldv<false>(W3, k*64 + pc);
            sh.WT[2][kk] = (_Float16)ldv<false>(W4, k*64 + c);
        }
    }
    // W1' fragment table: rows k=0..16 -> W1, k=17 -> b1, k>=18 -> 0.
    for (int i = tid; i < 2048; i += 512) {
        int k = i & 31, c = i >> 5;
        int kk = c*32 + (k ^ ((c & 3) << 3));
        int pc = dp_pi(c);
        float v = 0.f;
        if (F32) {
            if (k < 17)       v = ldv<true>(W1, k*64 + pc);
            else if (k == 17) v = ldv<true>(b1, pc);
        } else {
            if (k < 17)       v = ldv<false>(W1, k*64 + pc);
            else if (k == 17) v = ldv<false>(b1, pc);
        }
        sh.A1L[kk] = (_Float16)v;
    }
    if (tid < 64) {
        int ps = dp_pi(tid);
        sh.bD[0][tid] = F32 ? ldv<true>(b2, ps) : ldv<false>(b2, ps);
        sh.bD[1][tid] = F32 ? ldv<true>(b3, ps) : ldv<false>(b3, ps);
    }

    const int lane = tid & 63;
    const int wid  = tid >> 6;
    const int col  = lane & 15;
    const int g    = lane >> 4;
    const int sw8  = (col & 7) << 3;
    const int sw5  = (col & 3) << 3;

    float b4r[4];
    #pragma unroll
    for (int t = 0; t < 4; t++)
        b4r[t] = F32 ? ldv<true>(b4, 16*t + col) : ldv<false>(b4, 16*t + col);

    __syncthreads();

    float* RlA = sh.Rl[wid];
    float* RlB = sh.Rl[wid] + 64;
    int* nb = sh.nb[wid];

    const int w = blockIdx.x*8 + wid;
    const int n_lo = wstart[w];
    const int n_hi = wstart[w+1];
    const int nbn  = n_hi - n_lo;

    for (int j = lane; j < nbn && j < 64; j += 64) nb[j] = poffs[n_lo + 1 + j];

    if (n_lo >= n_hi) return;   // no nodes for this wave (no barriers below)

    auto nodeEnd = [&](int nd) -> int {
        int idx = nd - n_lo;
        return (idx < 64) ? nb[idx] : poffs[nd + 1];
    };

    const int pS = poffs[n_lo];
    const int pE = nodeEnd(n_hi - 1);

    int node = n_lo;
    int p1n  = nodeEnd(node);

    f32x2 gr01[4] = {{0,0},{0,0},{0,0},{0,0}};
    f32x2 gr23[4] = {{0,0},{0,0},{0,0},{0,0}};

    auto finishNode = [&](int nodeId) {
        float grf[4][4];
        #pragma unroll
        for (int t = 0; t < 4; t++) {
            grf[0][t] = gr01[t].x; grf[1][t] = gr01[t].y;
            grf[2][t] = gr23[t].x; grf[3][t] = gr23[t].y;
            gr01[t].x = 0.f; gr01[t].y = 0.f;
            gr23[t].x = 0.f; gr23[t].y = 0.f;
        }
        #pragma unroll
        for (int a = 0; a < 4; a++)
            #pragma unroll
            for (int t = 0; t < 4; t++) {
                float v = grf[a][t];
                v += __shfl_xor(v, 16);
                v += __shfl_xor(v, 32);
                grf[a][t] = v;
            }
        float gs0[4], gs1[4];
        #pragma unroll
        for (int a = 0; a < 4; a++) {
            gs0[a] = __shfl(grf[a][0], 2*g);
            gs1[a] = __shfl(grf[a][0], 2*g + 1);
        }
        #pragma unroll
        for (int t = 0; t < 4; t++) {
            float e0 = 0.f, e1 = 0.f;
            #pragma unroll
            for (int a = 0; a < 4; a++) {
                e0 = fmaf(grf[a][t], gs0[a], e0);
                e1 = fmaf(grf[a][t], gs1[a], e1);
            }
            float2 st; st.x = e0; st.y = e1;
            *(float2*)&out[(size_t)nodeId*512 + (16*t + col)*8 + 2*g] = st;
        }
    };

    // GR stage for one 16-slot group at stream offset s: hoisted G (layer-4
    // MFMA once per group), then a pure-VALU node-segment walk over R.
    auto grPhase = [&](const half8& h0, const half8& h1, const float* Rlp, int s) {
        f32x4 G4[4];
        #pragma unroll
        for (int t = 0; t < 4; t++) {
            const int wb = (16*t + col)*64;
            half8 w0 = *(const half8*)&sh.WT[2][wb + ((8*g) ^ sw8)];
            half8 w1 = *(const half8*)&sh.WT[2][wb + ((32 + 8*g) ^ sw8)];
            f32x4 c4 = {b4r[t], b4r[t], b4r[t], b4r[t]};
            f32x4 G = __builtin_amdgcn_mfma_f32_16x16x32_f16(h0, w0, c4, 0, 0, 0);
            G4[t] = __builtin_amdgcn_mfma_f32_16x16x32_f16(h1, w1, G, 0, 0, 0);
        }
        int segstart = s;
        while (true) {
            while (node < n_hi && p1n <= segstart) {
                finishNode(node);
                node++;
                if (node < n_hi) p1n = nodeEnd(node);
            }
            if (node >= n_hi || segstart >= s + 16) break;
            int segend = (p1n < s + 16) ? p1n : (s + 16);
            const int lo = segstart - s, hi = segend - s;
            #pragma unroll
            for (int j = 0; j < 4; j++) {
                int r = 4*g + j;
                float m = ((unsigned)(r - lo) < (unsigned)(hi - lo)) ? 1.0f : 0.0f;
                f32x4 Rj = *(const f32x4*)&Rlp[16*g + 4*j];
                f32x2 Rlm = lo2(Rj) * m;
                f32x2 Rhm = hi2(Rj) * m;
                #pragma unroll
                for (int t = 0; t < 4; t++) {
                    f32x2 gs = {G4[t][j], G4[t][j]};
                    gr01[t] = __builtin_elementwise_fma(gs, Rlm, gr01[t]);
                    gr23[t] = __builtin_elementwise_fma(gs, Rhm, gr23[t]);
                }
            }
            segstart = segend;
        }
    };

    // sparse layer-1 B-fragment built in registers:
    // x[k] = (k==0)? sij : (k==z+1 || k==17) ? 1 : 0 ; k = 8g+i
    auto build_x = [&](float sij, int z) -> half8 {
        half8 x;
        const int ku = 8*g;
        const _Float16 s16 = (_Float16)sij;
        const int zk = z + 1;
        #pragma unroll
        for (int i = 0; i < 8; i++) {
            int k = ku + i;
            _Float16 v = (k == zk || k == 17) ? (_Float16)1.0f : (_Float16)0.0f;
            if (k == 0) v = s16;
            x[i] = v;
        }
        return x;
    };

    const f32x4 zero4 = {0.f, 0.f, 0.f, 0.f};
    const int ngs = (pE - pS + 15) >> 4;   // stream groups for this wave

    int k = 0;
    // ================= paired stream groups =================
    for (; k + 2 <= ngs; k += 2) {
        const int sA = pS + 16*k;
        const int sB = sA + 16;
        uint4 rcA = srec[sA + col];          // A always fully valid
        int slotB = sB + col;
        const bool vB = slotB < pE;
        slotB = slotB < NEDGE-1 ? slotB : NEDGE-1;
        uint4 rcB = srec[slotB];
        if (!vB) { rcB.x = 0u; rcB.y = 0u; rcB.z = 0u; rcB.w = 0u; }
        const float sijA = __uint_as_float(rcA.x);
        const float sijB = __uint_as_float(rcB.x);
        const int zA = (int)(rcA.x & 15u);
        const int zB = (int)(rcB.x & 15u);
        if (g == 0) {
            *(uint4*)&RlA[col*4] = rcA;
            *(uint4*)&RlB[col*4] = rcB;
        }

        // ---- layer 1 via MFMA (LDS W1' fragments shared A/B, sparse B in regs)
        half8 h0A, h1A, h0B, h1B;
        {
            half8 a1f[4];
            #pragma unroll
            for (int t = 0; t < 4; t++)
                a1f[t] = *(const half8*)&sh.A1L[(16*t + col)*32 + ((8*g) ^ sw5)];
            half8 xfA = build_x(sijA, zA);
            half8 xfB = build_x(sijB, zB);
            f32x4 p1A[4], p1B[4];
            #pragma unroll
            for (int t = 0; t < 4; t++) {
                p1A[t] = __builtin_amdgcn_mfma_f32_16x16x32_f16(a1f[t], xfA, zero4, 0, 0, 0);
                p1B[t] = __builtin_amdgcn_mfma_f32_16x16x32_f16(a1f[t], xfB, zero4, 0, 0, 0);
            }
            repack_silu(p1A, h0A, h1A);
            repack_silu(p1B, h0B, h1B);
        }

        f32x4 accA[4], accB[4];

        // ---- layer 2 (shared weight/bias reads)
        #pragma unroll
        for (int t = 0; t < 4; t++) {
            const int wb = (16*t + col)*64;
            half8 w0 = *(const half8*)&sh.WT[0][wb + ((8*g) ^ sw8)];
            half8 w1 = *(const half8*)&sh.WT[0][wb + ((32 + 8*g) ^ sw8)];
            f32x4 cb = *(const f32x4*)&sh.bD[0][16*t + 4*g];
            f32x4 a = __builtin_amdgcn_mfma_f32_16x16x32_f16(w0, h0A, cb, 0, 0, 0);
            accA[t]  = __builtin_amdgcn_mfma_f32_16x16x32_f16(w1, h1A, a, 0, 0, 0);
            f32x4 b = __builtin_amdgcn_mfma_f32_16x16x32_f16(w0, h0B, cb, 0, 0, 0);
            accB[t]  = __builtin_amdgcn_mfma_f32_16x16x32_f16(w1, h1B, b, 0, 0, 0);
        }
        repack_silu(accA, h0A, h1A);
        repack_silu(accB, h0B, h1B);

        // ---- layer 3
        #pragma unroll
        for (int t = 0; t < 4; t++) {
            const int wb = (16*t + col)*64;
            half8 w0 = *(const half8*)&sh.WT[1][wb + ((8*g) ^ sw8)];
            half8 w1 = *(const half8*)&sh.WT[1][wb + ((32 + 8*g) ^ sw8)];
            f32x4 cb = *(const f32x4*)&sh.bD[1][16*t + 4*g];
            f32x4 a = __builtin_amdgcn_mfma_f32_16x16x32_f16(w0, h0A, cb, 0, 0, 0);
            accA[t]  = __builtin_amdgcn_mfma_f32_16x16x32_f16(w1, h1A, a, 0, 0, 0);
            f32x4 b = __builtin_amdgcn_mfma_f32_16x16x32_f16(w0, h0B, cb, 0, 0, 0);
            accB[t]  = __builtin_amdgcn_mfma_f32_16x16x32_f16(w1, h1B, b, 0, 0, 0);
        }
        repack_silu(accA, h0A, h1A);
        repack_silu(accB, h0B, h1B);

        // ---- layer 4 + GR, segmented by node boundaries
        grPhase(h0A, h1A, RlA, sA);
        grPhase(h0B, h1B, RlB, sB);
    }

    // ================= odd tail stream group =================
    if (k < ngs) {
        const int sA = pS + 16*k;
        int slot = sA + col;
        const bool v = slot < pE;
        slot = slot < NEDGE-1 ? slot : NEDGE-1;
        uint4 rc = srec[slot];
        if (!v) { rc.x = 0u; rc.y = 0u; rc.z = 0u; rc.w = 0u; }
        const float sij = __uint_as_float(rc.x);
        const int z = (int)(rc.x & 15u);
        if (g == 0) {
            *(uint4*)&RlA[col*4] = rc;
        }

        half8 h0, h1;
        {
            half8 a1f[4];
            #pragma unroll
            for (int t = 0; t < 4; t++)
                a1f[t] = *(const half8*)&sh.A1L[(16*t + col)*32 + ((8*g) ^ sw5)];
            half8 xf = build_x(sij, z);
            f32x4 p1[4];
            #pragma unroll
            for (int t = 0; t < 4; t++)
                p1[t] = __builtin_amdgcn_mfma_f32_16x16x32_f16(a1f[t], xf, zero4, 0, 0, 0);
            repack_silu(p1, h0, h1);
        }

        f32x4 acc[4];
        #pragma unroll
        for (int t = 0; t < 4; t++) {
            const int wb = (16*t + col)*64;
            half8 w0 = *(const half8*)&sh.WT[0][wb + ((8*g) ^ sw8)];
            half8 w1 = *(const half8*)&sh.WT[0][wb + ((32 + 8*g) ^ sw8)];
            f32x4 cb = *(const f32x4*)&sh.bD[0][16*t + 4*g];
            f32x4 a = __builtin_amdgcn_mfma_f32_16x16x32_f16(w0, h0, cb, 0, 0, 0);
            acc[t]  = __builtin_amdgcn_mfma_f32_16x16x32_f16(w1, h1, a, 0, 0, 0);
        }
        repack_silu(acc, h0, h1);

        #pragma unroll
        for (int t = 0; t < 4; t++) {
            const int wb = (16*t + col)*64;
            half8 w0 = *(const half8*)&sh.WT[1][wb + ((8*g) ^ sw8)];
            half8 w1 = *(const half8*)&sh.WT[1][wb + ((32 + 8*g) ^ sw8)];
            f32x4 cb = *(const f32x4*)&sh.bD[1][16*t + 4*g];
            f32x4 a = __builtin_amdgcn_mfma_f32_16x16x32_f16(w0, h0, cb, 0, 0, 0);
            acc[t]  = __builtin_amdgcn_mfma_f32_16x16x32_f16(w1, h1, a, 0, 0, 0);
        }
        repack_silu(acc, h0, h1);

        grPhase(h0, h1, RlA, sA);
    }

    // finish remaining nodes (last node + any trailing empty nodes)
    while (node < n_hi) {
        finishNode(node);
        node++;
    }
}

// ---------------------------------------------------------------------------
extern "C" void kernel_launch(void* const* d_in, const int* in_sizes, int n_in,
                              void* d_out, int out_size, void* d_ws, size_t ws_size,
                              hipStream_t stream)
{
    const int* species = (const int*)d_in[0];
    const int* esrc    = (const int*)d_in[1];
    const int* edst    = (const int*)d_in[2];
    const void* dist = d_in[3];
    const void* swt  = d_in[4];
    const void* vec  = d_in[5];
    const void* W1 = d_in[6];
    const void* b1 = d_in[7];
    const void* W2 = d_in[8];
    const void* b2 = d_in[9];
    const void* W3 = d_in[10];
    const void* b3 = d_in[11];
    const void* W4 = d_in[12];
    const void* b4 = d_in[13];
    float* out = (float*)d_out;

    char* base = (char*)d_ws;
    size_t off = 0;
    int* flag  = (int*)(base + off);    off += 256;
    uint4* srec = (uint4*)(base + off); off += (size_t)NEDGE*16;     // 25.6 MB dense
    int* counts = (int*)(base + off);   off += (size_t)NNODE*4;
    int* poffs  = (int*)(base + off);   off += (size_t)(NNODE+1)*4 + 12;
    int* rank   = (int*)(base + off);   off += (size_t)NEDGE*4;      // 6.4 MB
    int* wstart = (int*)(base + off);   off += (size_t)(NWAVES+1)*4 + 12;
    int* bsum   = (int*)(base + off);   off += 1024;
    int* bpre   = (int*)(base + off);   off += 1024;
    (void)ws_size; (void)in_sizes; (void)n_in; (void)out_size;

    (void)hipMemsetAsync(counts, 0, (size_t)NNODE*4, stream);

    dp_hist<<<NEDGE/256, 256, 0, stream>>>(esrc, counts, rank,
                                           (const unsigned int*)dist, flag);
    dp_s1<<<SCAN_BLOCKS, 256, 0, stream>>>(counts, bsum);
    dp_s2<<<1, 256, 0, stream>>>(bsum, bpre);
    dp_s3<<<SCAN_BLOCKS, 256, 0, stream>>>(counts, bpre, poffs);
    dp_scat<<<NEDGE/256, 256, 0, stream>>>(flag, esrc, edst, species,
                                           dist, swt, vec, poffs, rank, srec, wstart);
    dp_fused<<<NBLOCKS, 512, 0, stream>>>(flag, W1, b1, W2, b2, W3, b3, W4, b4,
                                          poffs, wstart, srec, out);
}

// Round 6
// 264.618 us; speedup vs baseline: 1.0073x; 1.0073x over previous
//
#include <hip/hip_runtime.h>

#define NNODE 50000
#define NEDGE 1600000
#define NBLOCKS 1024      // 4 blocks/CU
#define NWAVES (NBLOCKS*8)
#define EPW 196           // ceil(NEDGE/NWAVES)

typedef __attribute__((ext_vector_type(8))) _Float16 half8;
typedef __attribute__((ext_vector_type(2))) __fp16 fp16x2;
typedef __attribute__((ext_vector_type(4))) float f32x4;
typedef __attribute__((ext_vector_type(2))) float f32x2;

union H2U { fp16x2 h; unsigned int u; };
union H8U { half8 h8; unsigned int u[4]; };

__device__ __forceinline__ float b2f(unsigned short u) {
    return __uint_as_float(((unsigned int)u) << 16);
}
__device__ __forceinline__ f32x2 lo2(f32x4 v) { f32x2 r; r.x = v[0]; r.y = v[1]; return r; }
__device__ __forceinline__ f32x2 hi2(f32x4 v) { f32x2 r; r.x = v[2]; r.y = v[3]; return r; }

// packed-pair silu -> packed f16 pair (v_pk_mul/add_f32 + 2x exp2/rcp + cvt_pkrtz)
__device__ __forceinline__ unsigned int silu2_pk(f32x2 x) {
    f32x2 u = x * (-1.44269504f);
    f32x2 e;
    e.x = __builtin_amdgcn_exp2f(u.x);
    e.y = __builtin_amdgcn_exp2f(u.y);
    f32x2 d = e + 1.0f;
    f32x2 r;
    r.x = __builtin_amdgcn_rcpf(d.x);
    r.y = __builtin_amdgcn_rcpf(d.y);
    f32x2 s = x * r;
    H2U h2; h2.h = __builtin_amdgcn_cvt_pkrtz(s.x, s.y);
    return h2.u;
}

// channel permutation folding the MFMA D-layout into the next layer's
// B-fragment layout (cols of W2/W3 only; repack restores true space).
__device__ __forceinline__ int dp_pi(int s) {
    return (((s >> 5) & 1) << 5) | (((s >> 2) & 3) << 3)
         | (((s >> 4) & 1) << 2) | (s & 3);
}
__device__ __forceinline__ void repack_silu(const f32x4 acc[4], half8& b0, half8& b1) {
    H8U u0, u1;
    u0.u[0] = silu2_pk(lo2(acc[0])); u0.u[1] = silu2_pk(hi2(acc[0]));
    u0.u[2] = silu2_pk(lo2(acc[1])); u0.u[3] = silu2_pk(hi2(acc[1]));
    u1.u[0] = silu2_pk(lo2(acc[2])); u1.u[1] = silu2_pk(hi2(acc[2]));
    u1.u[2] = silu2_pk(lo2(acc[3])); u1.u[3] = silu2_pk(hi2(acc[3]));
    b0 = u0.h8; b1 = u1.h8;
}

template<bool F32>
__device__ __forceinline__ float ldv(const void* p, int i) {
    return F32 ? ((const float*)p)[i] : b2f(((const unsigned short*)p)[i]);
}

__device__ __forceinline__ int lb_poffs(const int* __restrict__ poffs, int val) {
    int lo = 0, hi = NNODE;
    while (lo < hi) { int mid = (lo + hi) >> 1; if (poffs[mid] < val) lo = mid + 1; else hi = mid; }
    return lo;
}

// ---------------------------------------------------------------------------
// hist (+ input-dtype probe in block 0) + per-edge rank record.
// ---------------------------------------------------------------------------
__global__ void dp_hist(const int* __restrict__ esrc, int* __restrict__ counts,
                        int* __restrict__ rank,
                        const unsigned int* __restrict__ dw, int* __restrict__ flag) {
    if (blockIdx.x == 0 && threadIdx.x < 64) {
        const int lane = threadIdx.x;
        unsigned int w = dw[lane];
        unsigned int hb_ = (w >> 8) & 0xFF;
        bool bf16like = (hb_ == 0x3F) || (hb_ == 0x40);
        unsigned long long m = __ballot(bf16like);
        if (lane == 0) *flag = (__popcll(m) > 32) ? 0 : 1;
    }
    int i = blockIdx.x*256 + threadIdx.x;
    if (i < NEDGE) rank[i] = atomicAdd(&counts[esrc[i]], 1);
}

// ---------------------------------------------------------------------------
// Single-block exclusive scan over counts[0..NNODE) -> poffs[0..NNODE].
// Replaces the previous 3-kernel chain (s1/s2/s3): one launch, 13 iterations
// of 4096 elements (int4 per thread), wave shfl-scan + 16-wave LDS scan,
// carry kept in registers (no cross-iteration shared-var races).
// ---------------------------------------------------------------------------
__global__ __launch_bounds__(1024) void dp_scan(const int* __restrict__ counts,
                                                int* __restrict__ poffs) {
    __shared__ int wpre[16];
    const int tid = threadIdx.x;
    const int lane = tid & 63;
    const int wid  = tid >> 6;
    int base = 0;
    for (int it = 0; it < 13; ++it) {
        const int i = it*4096 + tid*4;
        int c0 = (i+0 < NNODE) ? counts[i+0] : 0;
        int c1 = (i+1 < NNODE) ? counts[i+1] : 0;
        int c2 = (i+2 < NNODE) ? counts[i+2] : 0;
        int c3 = (i+3 < NNODE) ? counts[i+3] : 0;
        const int s = c0 + c1 + c2 + c3;
        int v = s;
        #pragma unroll
        for (int o = 1; o < 64; o <<= 1) {
            int x = __shfl_up(v, o);
            if (lane >= o) v += x;
        }
        if (lane == 63) wpre[wid] = v;
        __syncthreads();
        if (tid < 16) {
            int t = wpre[tid];
            #pragma unroll
            for (int o = 1; o < 16; o <<= 1) {
                int x = __shfl_up(t, o);
                if (tid >= o) t += x;
            }
            wpre[tid] = t;
        }
        __syncthreads();
        const int wb  = (wid > 0) ? wpre[wid-1] : 0;
        const int tot = wpre[15];
        const int e0  = base + wb + (v - s);
        if (i + 3 <= NNODE) {
            int4 st;
            st.x = e0;
            st.y = e0 + c0;
            st.z = e0 + c0 + c1;
            st.w = e0 + c0 + c1 + c2;
            *(int4*)&poffs[i] = st;
        } else if (i <= NNODE) {
            int e = e0;
            int cc[4] = {c0, c1, c2, c3};
            #pragma unroll
            for (int j = 0; j < 4; ++j) {
                if (i + j <= NNODE) { poffs[i+j] = e; e += cc[j]; }
            }
        }
        base += tot;
        __syncthreads();
    }
}

// ---------------------------------------------------------------------------
// Scatter + per-edge prep, atomic-free, DENSE positions. Also computes the
// per-wave node-range starts (wstart) in the first blocks.
// ---------------------------------------------------------------------------
template<bool F32>
__device__ __forceinline__ void scat_body(
    const int* __restrict__ esrc, const int* __restrict__ edst,
    const int* __restrict__ species,
    const void* __restrict__ dist, const void* __restrict__ swt,
    const void* __restrict__ vec,
    const int* __restrict__ poffs, const int* __restrict__ rank,
    uint4* __restrict__ srec)
{
    int i = blockIdx.x*256 + threadIdx.x;
    if (i >= NEDGE) return;
    int pe = poffs[esrc[i]] + rank[i];
    float d  = ldv<F32>(dist, i);
    float sw = ldv<F32>(swt, i);
    float inv = 1.0f / d;
    float sij = sw * inv;
    float rx = sij * ldv<F32>(vec, 3*i+0) * inv;
    float ry = sij * ldv<F32>(vec, 3*i+1) * inv;
    float rz = sij * ldv<F32>(vec, 3*i+2) * inv;
    int z = species[edst[i]] & 15;
    uint4 rc;
    rc.x = (__float_as_uint(sij) & ~15u) | (unsigned)z;
    rc.y = __float_as_uint(rx);
    rc.z = __float_as_uint(ry);
    rc.w = __float_as_uint(rz);
    srec[pe] = rc;
}

__global__ void dp_scat(const int* __restrict__ flagp,
                        const int* __restrict__ esrc, const int* __restrict__ edst,
                        const int* __restrict__ species,
                        const void* __restrict__ dist, const void* __restrict__ swt,
                        const void* __restrict__ vec,
                        const int* __restrict__ poffs, const int* __restrict__ rank,
                        uint4* __restrict__ srec, int* __restrict__ wstart)
{
    int i = blockIdx.x*256 + threadIdx.x;
    if (i <= NWAVES) wstart[i] = lb_poffs(poffs, i*EPW);
    if (*flagp) scat_body<true >(esrc, edst, species, dist, swt, vec, poffs, rank, srec);
    else        scat_body<false>(esrc, edst, species, dist, swt, vec, poffs, rank, srec);
}

// ---------------------------------------------------------------------------
// Fused MLP + aggregation + embedding. Node-decoupled group stream.
// UNCHANGED from the best-measured 154.3us version (control for this round).
// ---------------------------------------------------------------------------
struct __align__(16) FusedShared {
    _Float16 WT[3][4096];   // [L][c*64 + (k ^ ((c&7)<<3))]
    float W1z[16*68];
    float W1r0[64];
    float bD[2][64];        // b2[pi(s)], b3[pi(s)]
    float Rl[8][128];       // per-wave R: A 0..63, B 64..127
    int nb[8][64];          // per-wave node-boundary cache poffs[n_lo+1+j]
};                          // 35840 B -> 4 blocks/CU

__global__ __launch_bounds__(512, 4) void dp_fused(
    const int* __restrict__ flagp,
    const void* __restrict__ W1, const void* __restrict__ b1,
    const void* __restrict__ W2, const void* __restrict__ b2,
    const void* __restrict__ W3, const void* __restrict__ b3,
    const void* __restrict__ W4, const void* __restrict__ b4,
    const int* __restrict__ poffs, const int* __restrict__ wstart,
    const uint4* __restrict__ srec,
    float* __restrict__ out)
{
    __shared__ FusedShared sh;
    const bool F32 = (*flagp != 0);
    const int tid = threadIdx.x;

    for (int i = tid; i < 4096; i += 512) {
        int k = i >> 6, c = i & 63;
        int kk = c*64 + (k ^ ((c & 7) << 3));
        int pc = dp_pi(c);
        if (F32) {
            sh.WT[0][kk] = (_Float16)ldv<true>(W2, k*64 + pc);
            sh.WT[1][kk] = (_Float16)ldv<true>(W3, k*64 + pc);
            sh.WT[2][kk] = (_Float16)ldv<true>(W4, k*64 + c);
        } else {
            sh.WT[0][kk] = (_Float16)ldv<false>(W2, k*64 + pc);
            sh.WT[1][kk] = (_Float16)ldv<false>(W3, k*64 + pc);
            sh.WT[2][kk] = (_Float16)ldv<false>(W4, k*64 + c);
        }
    }
    for (int i = tid; i < 16*64; i += 512) {
        int z = i >> 6, j = i & 63;
        sh.W1z[z*68 + j] = (F32 ? (ldv<true>(W1,(1+z)*64+j) + ldv<true>(b1,j))
                                : (ldv<false>(W1,(1+z)*64+j) + ldv<false>(b1,j)));
    }
    if (tid < 64) {
        int ps = dp_pi(tid);
        sh.W1r0[tid] = F32 ? ldv<true>(W1, tid) : ldv<false>(W1, tid);
        sh.bD[0][tid] = F32 ? ldv<true>(b2, ps) : ldv<false>(b2, ps);
        sh.bD[1][tid] = F32 ? ldv<true>(b3, ps) : ldv<false>(b3, ps);
    }

    const int lane = tid & 63;
    const int wid  = tid >> 6;
    const int col  = lane & 15;
    const int g    = lane >> 4;
    const int sw8  = (col & 7) << 3;

    float b4r[4];
    #pragma unroll
    for (int t = 0; t < 4; t++)
        b4r[t] = F32 ? ldv<true>(b4, 16*t + col) : ldv<false>(b4, 16*t + col);

    __syncthreads();

    float* RlA = sh.Rl[wid];
    float* RlB = sh.Rl[wid] + 64;
    int* nb = sh.nb[wid];

    const int w = blockIdx.x*8 + wid;
    const int n_lo = wstart[w];
    const int n_hi = wstart[w+1];
    const int nbn  = n_hi - n_lo;

    // cache node boundaries poffs[n_lo+1 .. n_hi] (<=64 typical; guarded)
    for (int j = lane; j < nbn && j < 64; j += 64) nb[j] = poffs[n_lo + 1 + j];

    if (n_lo >= n_hi) return;   // no nodes for this wave (no barriers below)

    auto nodeEnd = [&](int nd) -> int {
        int idx = nd - n_lo;
        return (idx < 64) ? nb[idx] : poffs[nd + 1];
    };

    const int pS = poffs[n_lo];
    const int pE = nodeEnd(n_hi - 1);

    int node = n_lo;
    int p1n  = nodeEnd(node);

    // GR accumulator packed along 'a': gr01[t] = (gr[a=0][t], gr[a=1][t])
    f32x2 gr01[4] = {{0,0},{0,0},{0,0},{0,0}};
    f32x2 gr23[4] = {{0,0},{0,0},{0,0},{0,0}};

    auto finishNode = [&](int nodeId) {
        float grf[4][4];
        #pragma unroll
        for (int t = 0; t < 4; t++) {
            grf[0][t] = gr01[t].x; grf[1][t] = gr01[t].y;
            grf[2][t] = gr23[t].x; grf[3][t] = gr23[t].y;
            gr01[t].x = 0.f; gr01[t].y = 0.f;
            gr23[t].x = 0.f; gr23[t].y = 0.f;
        }
        #pragma unroll
        for (int a = 0; a < 4; a++)
            #pragma unroll
            for (int t = 0; t < 4; t++) {
                float v = grf[a][t];
                v += __shfl_xor(v, 16);
                v += __shfl_xor(v, 32);
                grf[a][t] = v;
            }
        float gs0[4], gs1[4];
        #pragma unroll
        for (int a = 0; a < 4; a++) {
            gs0[a] = __shfl(grf[a][0], 2*g);
            gs1[a] = __shfl(grf[a][0], 2*g + 1);
        }
        #pragma unroll
        for (int t = 0; t < 4; t++) {
            float e0 = 0.f, e1 = 0.f;
            #pragma unroll
            for (int a = 0; a < 4; a++) {
                e0 = fmaf(grf[a][t], gs0[a], e0);
                e1 = fmaf(grf[a][t], gs1[a], e1);
            }
            float2 st; st.x = e0; st.y = e1;
            *(float2*)&out[(size_t)nodeId*512 + (16*t + col)*8 + 2*g] = st;
        }
    };

    // layer-4 + GR accumulate over rows [lo,hi) of the group (R masked).
    auto l4pass = [&](const half8& h0, const half8& h1, const float* Rlp,
                      int lo, int hi) {
        f32x4 Rm[4];
        #pragma unroll
        for (int j = 0; j < 4; j++) {
            int r = 4*g + j;
            float m = ((unsigned)(r - lo) < (unsigned)(hi - lo)) ? 1.0f : 0.0f;
            f32x4 Rj = *(const f32x4*)&Rlp[16*g + 4*j];
            Rm[j] = Rj * m;
        }
        #pragma unroll
        for (int t = 0; t < 4; t++) {
            const int wb = (16*t + col)*64;
            half8 w0 = *(const half8*)&sh.WT[2][wb + ((8*g) ^ sw8)];
            half8 w1 = *(const half8*)&sh.WT[2][wb + ((32 + 8*g) ^ sw8)];
            f32x4 c4 = {b4r[t], b4r[t], b4r[t], b4r[t]};
            f32x4 G = __builtin_amdgcn_mfma_f32_16x16x32_f16(h0, w0, c4, 0, 0, 0);
            G = __builtin_amdgcn_mfma_f32_16x16x32_f16(h1, w1, G, 0, 0, 0);
            #pragma unroll
            for (int j = 0; j < 4; j++) {
                f32x2 gs = {G[j], G[j]};
                gr01[t] = __builtin_elementwise_fma(gs, lo2(Rm[j]), gr01[t]);
                gr23[t] = __builtin_elementwise_fma(gs, hi2(Rm[j]), gr23[t]);
            }
        }
    };

    // GR stage for one 16-slot group at stream offset s: walk node segments.
    auto grPhase = [&](const half8& h0, const half8& h1, const float* Rlp, int s) {
        int segstart = s;
        while (true) {
            while (node < n_hi && p1n <= segstart) {
                finishNode(node);
                node++;
                if (node < n_hi) p1n = nodeEnd(node);
            }
            if (node >= n_hi || segstart >= s + 16) break;
            int segend = (p1n < s + 16) ? p1n : (s + 16);
            l4pass(h0, h1, Rlp, segstart - s, segend - s);
            segstart = segend;
        }
    };

    const int ngs = (pE - pS + 15) >> 4;   // stream groups for this wave

    int k = 0;
    // ================= paired stream groups =================
    for (; k + 2 <= ngs; k += 2) {
        const int sA = pS + 16*k;
        const int sB = sA + 16;
        uint4 rcA = srec[sA + col];          // A always fully valid
        int slotB = sB + col;
        const bool vB = slotB < pE;
        slotB = slotB < NEDGE-1 ? slotB : NEDGE-1;
        uint4 rcB = srec[slotB];
        if (!vB) { rcB.x = 0u; rcB.y = 0u; rcB.z = 0u; rcB.w = 0u; }
        const float sijA = __uint_as_float(rcA.x);
        const float sijB = __uint_as_float(rcB.x);
        const int zA = (int)(rcA.x & 15u);
        const int zB = (int)(rcB.x & 15u);
        if (g == 0) {
            *(uint4*)&RlA[col*4] = rcA;
            *(uint4*)&RlB[col*4] = rcB;
        }

        // ---- layer 1 both (packed-fp32 fma + packed silu -> f16 pairs)
        half8 h0A, h1A, h0B, h1B;
        {
            const float* wzA = &sh.W1z[zA*68];
            const float* wzB = &sh.W1z[zB*68];
            f32x4 r0 = *(const f32x4*)&sh.W1r0[8*g];
            f32x4 r1 = *(const f32x4*)&sh.W1r0[8*g + 4];
            f32x4 r2 = *(const f32x4*)&sh.W1r0[32 + 8*g];
            f32x4 r3 = *(const f32x4*)&sh.W1r0[32 + 8*g + 4];
            f32x4 a0 = *(const f32x4*)&wzA[8*g];
            f32x4 a1 = *(const f32x4*)&wzA[8*g + 4];
            f32x4 a2 = *(const f32x4*)&wzA[32 + 8*g];
            f32x4 a3 = *(const f32x4*)&wzA[32 + 8*g + 4];
            f32x4 c0 = *(const f32x4*)&wzB[8*g];
            f32x4 c1 = *(const f32x4*)&wzB[8*g + 4];
            f32x4 c2 = *(const f32x4*)&wzB[32 + 8*g];
            f32x4 c3 = *(const f32x4*)&wzB[32 + 8*g + 4];
            f32x2 sA2 = {sijA, sijA};
            f32x2 sB2 = {sijB, sijB};
            H8U u0A, u1A, u0B, u1B;
            u0A.u[0] = silu2_pk(__builtin_elementwise_fma(sA2, lo2(r0), lo2(a0)));
            u0A.u[1] = silu2_pk(__builtin_elementwise_fma(sA2, hi2(r0), hi2(a0)));
            u0A.u[2] = silu2_pk(__builtin_elementwise_fma(sA2, lo2(r1), lo2(a1)));
            u0A.u[3] = silu2_pk(__builtin_elementwise_fma(sA2, hi2(r1), hi2(a1)));
            u1A.u[0] = silu2_pk(__builtin_elementwise_fma(sA2, lo2(r2), lo2(a2)));
            u1A.u[1] = silu2_pk(__builtin_elementwise_fma(sA2, hi2(r2), hi2(a2)));
            u1A.u[2] = silu2_pk(__builtin_elementwise_fma(sA2, lo2(r3), lo2(a3)));
            u1A.u[3] = silu2_pk(__builtin_elementwise_fma(sA2, hi2(r3), hi2(a3)));
            u0B.u[0] = silu2_pk(__builtin_elementwise_fma(sB2, lo2(r0), lo2(c0)));
            u0B.u[1] = silu2_pk(__builtin_elementwise_fma(sB2, hi2(r0), hi2(c0)));
            u0B.u[2] = silu2_pk(__builtin_elementwise_fma(sB2, lo2(r1), lo2(c1)));
            u0B.u[3] = silu2_pk(__builtin_elementwise_fma(sB2, hi2(r1), hi2(c1)));
            u1B.u[0] = silu2_pk(__builtin_elementwise_fma(sB2, lo2(r2), lo2(c2)));
            u1B.u[1] = silu2_pk(__builtin_elementwise_fma(sB2, hi2(r2), hi2(c2)));
            u1B.u[2] = silu2_pk(__builtin_elementwise_fma(sB2, lo2(r3), lo2(c3)));
            u1B.u[3] = silu2_pk(__builtin_elementwise_fma(sB2, hi2(r3), hi2(c3)));
            h0A = u0A.h8; h1A = u1A.h8;
            h0B = u0B.h8; h1B = u1B.h8;
        }

        f32x4 accA[4], accB[4];

        // ---- layer 2 (shared weight/bias reads)
        #pragma unroll
        for (int t = 0; t < 4; t++) {
            const int wb = (16*t + col)*64;
            half8 w0 = *(const half8*)&sh.WT[0][wb + ((8*g) ^ sw8)];
            half8 w1 = *(const half8*)&sh.WT[0][wb + ((32 + 8*g) ^ sw8)];
            f32x4 cb = *(const f32x4*)&sh.bD[0][16*t + 4*g];
            f32x4 a = __builtin_amdgcn_mfma_f32_16x16x32_f16(w0, h0A, cb, 0, 0, 0);
            accA[t]  = __builtin_amdgcn_mfma_f32_16x16x32_f16(w1, h1A, a, 0, 0, 0);
            f32x4 b = __builtin_amdgcn_mfma_f32_16x16x32_f16(w0, h0B, cb, 0, 0, 0);
            accB[t]  = __builtin_amdgcn_mfma_f32_16x16x32_f16(w1, h1B, b, 0, 0, 0);
        }
        repack_silu(accA, h0A, h1A);
        repack_silu(accB, h0B, h1B);

        // ---- layer 3
        #pragma unroll
        for (int t = 0; t < 4; t++) {
            const int wb = (16*t + col)*64;
            half8 w0 = *(const half8*)&sh.WT[1][wb + ((8*g) ^ sw8)];
            half8 w1 = *(const half8*)&sh.WT[1][wb + ((32 + 8*g) ^ sw8)];
            f32x4 cb = *(const f32x4*)&sh.bD[1][16*t + 4*g];
            f32x4 a = __builtin_amdgcn_mfma_f32_16x16x32_f16(w0, h0A, cb, 0, 0, 0);
            accA[t]  = __builtin_amdgcn_mfma_f32_16x16x32_f16(w1, h1A, a, 0, 0, 0);
            f32x4 b = __builtin_amdgcn_mfma_f32_16x16x32_f16(w0, h0B, cb, 0, 0, 0);
            accB[t]  = __builtin_amdgcn_mfma_f32_16x16x32_f16(w1, h1B, b, 0, 0, 0);
        }
        repack_silu(accA, h0A, h1A);
        repack_silu(accB, h0B, h1B);

        // ---- layer 4 + GR, segmented by node boundaries
        grPhase(h0A, h1A, RlA, sA);
        grPhase(h0B, h1B, RlB, sB);
    }

    // ================= odd tail stream group =================
    if (k < ngs) {
        const int sA = pS + 16*k;
        int slot = sA + col;
        const bool v = slot < pE;
        slot = slot < NEDGE-1 ? slot : NEDGE-1;
        uint4 rc = srec[slot];
        if (!v) { rc.x = 0u; rc.y = 0u; rc.z = 0u; rc.w = 0u; }
        const float sij = __uint_as_float(rc.x);
        const int z = (int)(rc.x & 15u);
        if (g == 0) {
            *(uint4*)&RlA[col*4] = rc;
        }

        half8 h0, h1;
        {
            const float* wz = &sh.W1z[z*68];
            f32x4 a0 = *(const f32x4*)&wz[8*g];
            f32x4 a1 = *(const f32x4*)&wz[8*g + 4];
            f32x4 a2 = *(const f32x4*)&wz[32 + 8*g];
            f32x4 a3 = *(const f32x4*)&wz[32 + 8*g + 4];
            f32x4 r0 = *(const f32x4*)&sh.W1r0[8*g];
            f32x4 r1 = *(const f32x4*)&sh.W1r0[8*g + 4];
            f32x4 r2 = *(const f32x4*)&sh.W1r0[32 + 8*g];
            f32x4 r3 = *(const f32x4*)&sh.W1r0[32 + 8*g + 4];
            f32x2 s2 = {sij, sij};
            H8U u0, u1;
            u0.u[0] = silu2_pk(__builtin_elementwise_fma(s2, lo2(r0), lo2(a0)));
            u0.u[1] = silu2_pk(__builtin_elementwise_fma(s2, hi2(r0), hi2(a0)));
            u0.u[2] = silu2_pk(__builtin_elementwise_fma(s2, lo2(r1), lo2(a1)));
            u0.u[3] = silu2_pk(__builtin_elementwise_fma(s2, hi2(r1), hi2(a1)));
            u1.u[0] = silu2_pk(__builtin_elementwise_fma(s2, lo2(r2), lo2(a2)));
            u1.u[1] = silu2_pk(__builtin_elementwise_fma(s2, hi2(r2), hi2(a2)));
            u1.u[2] = silu2_pk(__builtin_elementwise_fma(s2, lo2(r3), lo2(a3)));
            u1.u[3] = silu2_pk(__builtin_elementwise_fma(s2, hi2(r3), hi2(a3)));
            h0 = u0.h8; h1 = u1.h8;
        }

        f32x4 acc[4];
        #pragma unroll
        for (int t = 0; t < 4; t++) {
            const int wb = (16*t + col)*64;
            half8 w0 = *(const half8*)&sh.WT[0][wb + ((8*g) ^ sw8)];
            half8 w1 = *(const half8*)&sh.WT[0][wb + ((32 + 8*g) ^ sw8)];
            f32x4 cb = *(const f32x4*)&sh.bD[0][16*t + 4*g];
            f32x4 a = __builtin_amdgcn_mfma_f32_16x16x32_f16(w0, h0, cb, 0, 0, 0);
            acc[t]  = __builtin_amdgcn_mfma_f32_16x16x32_f16(w1, h1, a, 0, 0, 0);
        }
        repack_silu(acc, h0, h1);

        #pragma unroll
        for (int t = 0; t < 4; t++) {
            const int wb = (16*t + col)*64;
            half8 w0 = *(const half8*)&sh.WT[1][wb + ((8*g) ^ sw8)];
            half8 w1 = *(const half8*)&sh.WT[1][wb + ((32 + 8*g) ^ sw8)];
            f32x4 cb = *(const f32x4*)&sh.bD[1][16*t + 4*g];
            f32x4 a = __builtin_amdgcn_mfma_f32_16x16x32_f16(w0, h0, cb, 0, 0, 0);
            acc[t]  = __builtin_amdgcn_mfma_f32_16x16x32_f16(w1, h1, a, 0, 0, 0);
        }
        repack_silu(acc, h0, h1);

        grPhase(h0, h1, RlA, sA);
    }

    // finish remaining nodes (last node + any trailing empty nodes)
    while (node < n_hi) {
        finishNode(node);
        node++;
    }
}

// ---------------------------------------------------------------------------
extern "C" void kernel_launch(void* const* d_in, const int* in_sizes, int n_in,
                              void* d_out, int out_size, void* d_ws, size_t ws_size,
                              hipStream_t stream)
{
    const int* species = (const int*)d_in[0];
    const int* esrc    = (const int*)d_in[1];
    const int* edst    = (const int*)d_in[2];
    const void* dist = d_in[3];
    const void* swt  = d_in[4];
    const void* vec  = d_in[5];
    const void* W1 = d_in[6];
    const void* b1 = d_in[7];
    const void* W2 = d_in[8];
    const void* b2 = d_in[9];
    const void* W3 = d_in[10];
    const void* b3 = d_in[11];
    const void* W4 = d_in[12];
    const void* b4 = d_in[13];
    float* out = (float*)d_out;

    char* base = (char*)d_ws;
    size_t off = 0;
    int* flag  = (int*)(base + off);    off += 256;
    uint4* srec = (uint4*)(base + off); off += (size_t)NEDGE*16;     // 25.6 MB dense
    int* counts = (int*)(base + off);   off += (size_t)NNODE*4;
    int* poffs  = (int*)(base + off);   off += (size_t)(NNODE+1)*4 + 12;
    int* rank   = (int*)(base + off);   off += (size_t)NEDGE*4;      // 6.4 MB
    int* wstart = (int*)(base + off);   off += (size_t)(NWAVES+1)*4 + 12;
    (void)ws_size; (void)in_sizes; (void)n_in; (void)out_size;

    (void)hipMemsetAsync(counts, 0, (size_t)NNODE*4, stream);

    dp_hist<<<NEDGE/256, 256, 0, stream>>>(esrc, counts, rank,
                                           (const unsigned int*)dist, flag);
    dp_scan<<<1, 1024, 0, stream>>>(counts, poffs);
    dp_scat<<<NEDGE/256, 256, 0, stream>>>(flag, esrc, edst, species,
                                           dist, swt, vec, poffs, rank, srec, wstart);
    dp_fused<<<NBLOCKS, 512, 0, stream>>>(flag, W1, b1, W2, b2, W3, b3, W4, b4,
                                          poffs, wstart, srec, out);
}

// Round 7
// 252.977 us; speedup vs baseline: 1.0537x; 1.0460x over previous
//
#include <hip/hip_runtime.h>

#define NNODE 50000
#define NEDGE 1600000
#define SCAN_BLOCKS 196   // ceil(50000/256)
#define NBLOCKS 1024      // 4 blocks/CU
#define NWAVES (NBLOCKS*8)
#define EPW 196           // ceil(NEDGE/NWAVES)

typedef __attribute__((ext_vector_type(8))) _Float16 half8;
typedef __attribute__((ext_vector_type(2))) __fp16 fp16x2;
typedef __attribute__((ext_vector_type(4))) float f32x4;
typedef __attribute__((ext_vector_type(2))) float f32x2;

union H2U { fp16x2 h; unsigned int u; };
union H8U { half8 h8; unsigned int u[4]; };

__device__ __forceinline__ float b2f(unsigned short u) {
    return __uint_as_float(((unsigned int)u) << 16);
}
__device__ __forceinline__ f32x2 lo2(f32x4 v) { f32x2 r; r.x = v[0]; r.y = v[1]; return r; }
__device__ __forceinline__ f32x2 hi2(f32x4 v) { f32x2 r; r.x = v[2]; r.y = v[3]; return r; }

// packed-pair silu -> packed f16 pair (v_pk_mul/add_f32 + 2x exp2/rcp + cvt_pkrtz)
__device__ __forceinline__ unsigned int silu2_pk(f32x2 x) {
    f32x2 u = x * (-1.44269504f);
    f32x2 e;
    e.x = __builtin_amdgcn_exp2f(u.x);
    e.y = __builtin_amdgcn_exp2f(u.y);
    f32x2 d = e + 1.0f;
    f32x2 r;
    r.x = __builtin_amdgcn_rcpf(d.x);
    r.y = __builtin_amdgcn_rcpf(d.y);
    f32x2 s = x * r;
    H2U h2; h2.h = __builtin_amdgcn_cvt_pkrtz(s.x, s.y);
    return h2.u;
}

// channel permutation folding the MFMA D-layout into the next layer's
// B-fragment layout (cols of W2/W3 only; repack restores true space).
__device__ __forceinline__ int dp_pi(int s) {
    return (((s >> 5) & 1) << 5) | (((s >> 2) & 3) << 3)
         | (((s >> 4) & 1) << 2) | (s & 3);
}
__device__ __forceinline__ void repack_silu(const f32x4 acc[4], half8& b0, half8& b1) {
    H8U u0, u1;
    u0.u[0] = silu2_pk(lo2(acc[0])); u0.u[1] = silu2_pk(hi2(acc[0]));
    u0.u[2] = silu2_pk(lo2(acc[1])); u0.u[3] = silu2_pk(hi2(acc[1]));
    u1.u[0] = silu2_pk(lo2(acc[2])); u1.u[1] = silu2_pk(hi2(acc[2]));
    u1.u[2] = silu2_pk(lo2(acc[3])); u1.u[3] = silu2_pk(hi2(acc[3]));
    b0 = u0.h8; b1 = u1.h8;
}

template<bool F32>
__device__ __forceinline__ float ldv(const void* p, int i) {
    return F32 ? ((const float*)p)[i] : b2f(((const unsigned short*)p)[i]);
}

__device__ __forceinline__ int lb_poffs(const int* __restrict__ poffs, int val) {
    int lo = 0, hi = NNODE;
    while (lo < hi) { int mid = (lo + hi) >> 1; if (poffs[mid] < val) lo = mid + 1; else hi = mid; }
    return lo;
}

// ---------------------------------------------------------------------------
// hist (+ input-dtype probe in block 0) + per-edge rank record.
// ---------------------------------------------------------------------------
__global__ void dp_hist(const int* __restrict__ esrc, int* __restrict__ counts,
                        int* __restrict__ rank,
                        const unsigned int* __restrict__ dw, int* __restrict__ flag) {
    if (blockIdx.x == 0 && threadIdx.x < 64) {
        const int lane = threadIdx.x;
        unsigned int w = dw[lane];
        unsigned int hb_ = (w >> 8) & 0xFF;
        bool bf16like = (hb_ == 0x3F) || (hb_ == 0x40);
        unsigned long long m = __ballot(bf16like);
        if (lane == 0) *flag = (__popcll(m) > 32) ? 0 : 1;
    }
    int i = blockIdx.x*256 + threadIdx.x;
    if (i < NEDGE) rank[i] = atomicAdd(&counts[esrc[i]], 1);
}

// s1: per-block unpadded sums
__global__ void dp_s1(const int* __restrict__ counts, int* __restrict__ bsum) {
    int i = blockIdx.x*256 + threadIdx.x;
    int v = (i < NNODE) ? counts[i] : 0;
    #pragma unroll
    for (int o = 32; o > 0; o >>= 1) v += __shfl_down(v, o);
    __shared__ int wsum[4];
    if ((threadIdx.x & 63) == 0) wsum[threadIdx.x >> 6] = v;
    __syncthreads();
    if (threadIdx.x == 0) bsum[blockIdx.x] = wsum[0] + wsum[1] + wsum[2] + wsum[3];
}

__global__ void dp_s2(const int* __restrict__ bsum, int* __restrict__ bpre) {
    __shared__ int sh[256];
    int t = threadIdx.x;
    int v = (t < SCAN_BLOCKS) ? bsum[t] : 0;
    sh[t] = v;
    __syncthreads();
    for (int o = 1; o < 256; o <<= 1) {
        int x = (t >= o) ? sh[t - o] : 0;
        __syncthreads();
        sh[t] += x;
        __syncthreads();
    }
    if (t < SCAN_BLOCKS) bpre[t] = sh[t] - v;
}

__global__ void dp_s3(const int* __restrict__ counts, const int* __restrict__ bpre,
                      int* __restrict__ poffs) {
    __shared__ int sh[256];
    int t = threadIdx.x;
    int i = blockIdx.x*256 + t;
    int c = (i < NNODE) ? counts[i] : 0;
    sh[t] = c;
    __syncthreads();
    for (int o = 1; o < 256; o <<= 1) {
        int x = (t >= o) ? sh[t - o] : 0;
        __syncthreads();
        sh[t] += x;
        __syncthreads();
    }
    int excl = sh[t] - c + bpre[blockIdx.x];
    if (i < NNODE) poffs[i] = excl;
    if (i == NNODE-1) poffs[NNODE] = excl + c;
}

// ---------------------------------------------------------------------------
// Scatter + per-edge prep, atomic-free, DENSE positions, 4 edges/thread
// (vectorized dense loads, 4 scattered 16B stores in flight -> ILP latency
// hiding; scat was issue/latency-bound at 1 edge/thread).
// Also computes the per-wave node-range starts (wstart).
// ---------------------------------------------------------------------------
template<bool F32>
__device__ __forceinline__ void scat_body4(
    const int* __restrict__ esrc, const int* __restrict__ edst,
    const int* __restrict__ species,
    const void* __restrict__ dist, const void* __restrict__ swt,
    const void* __restrict__ vec,
    const int* __restrict__ poffs, const int* __restrict__ rank,
    uint4* __restrict__ srec)
{
    const int i0 = (blockIdx.x*256 + threadIdx.x) * 4;
    if (i0 >= NEDGE) return;   // NEDGE % 4 == 0: all-or-nothing per thread
    int4 s4 = *(const int4*)&esrc[i0];
    int4 d4 = *(const int4*)&edst[i0];
    int4 r4 = *(const int4*)&rank[i0];
    float dd[4], sw[4], vv[12];
    if (F32) {
        const float4 t0 = *(const float4*)((const float*)dist + i0);
        const float4 t1 = *(const float4*)((const float*)swt + i0);
        dd[0]=t0.x; dd[1]=t0.y; dd[2]=t0.z; dd[3]=t0.w;
        sw[0]=t1.x; sw[1]=t1.y; sw[2]=t1.z; sw[3]=t1.w;
        const float* vp = (const float*)vec + 3*i0;   // 48B-aligned
        const float4 v0 = *(const float4*)(vp + 0);
        const float4 v1 = *(const float4*)(vp + 4);
        const float4 v2 = *(const float4*)(vp + 8);
        vv[0]=v0.x; vv[1]=v0.y; vv[2]=v0.z; vv[3]=v0.w;
        vv[4]=v1.x; vv[5]=v1.y; vv[6]=v1.z; vv[7]=v1.w;
        vv[8]=v2.x; vv[9]=v2.y; vv[10]=v2.z; vv[11]=v2.w;
    } else {
        const ushort4 t0 = *(const ushort4*)((const unsigned short*)dist + i0);
        const ushort4 t1 = *(const ushort4*)((const unsigned short*)swt + i0);
        dd[0]=b2f(t0.x); dd[1]=b2f(t0.y); dd[2]=b2f(t0.z); dd[3]=b2f(t0.w);
        sw[0]=b2f(t1.x); sw[1]=b2f(t1.y); sw[2]=b2f(t1.z); sw[3]=b2f(t1.w);
        const unsigned short* vp = (const unsigned short*)vec + 3*i0;  // 24B-aligned
        const ushort4 v0 = *(const ushort4*)(vp + 0);
        const ushort4 v1 = *(const ushort4*)(vp + 4);
        const ushort4 v2 = *(const ushort4*)(vp + 8);
        vv[0]=b2f(v0.x); vv[1]=b2f(v0.y); vv[2]=b2f(v0.z); vv[3]=b2f(v0.w);
        vv[4]=b2f(v1.x); vv[5]=b2f(v1.y); vv[6]=b2f(v1.z); vv[7]=b2f(v1.w);
        vv[8]=b2f(v2.x); vv[9]=b2f(v2.y); vv[10]=b2f(v2.z); vv[11]=b2f(v2.w);
    }
    const int sv[4] = {s4.x, s4.y, s4.z, s4.w};
    const int dv[4] = {d4.x, d4.y, d4.z, d4.w};
    const int rv[4] = {r4.x, r4.y, r4.z, r4.w};
    #pragma unroll
    for (int j = 0; j < 4; ++j) {
        const int pe = poffs[sv[j]] + rv[j];
        const float inv = 1.0f / dd[j];
        const float sij = sw[j] * inv;
        const float rx = sij * vv[3*j+0] * inv;
        const float ry = sij * vv[3*j+1] * inv;
        const float rz = sij * vv[3*j+2] * inv;
        const int z = species[dv[j]] & 15;
        uint4 rc;
        rc.x = (__float_as_uint(sij) & ~15u) | (unsigned)z;
        rc.y = __float_as_uint(rx);
        rc.z = __float_as_uint(ry);
        rc.w = __float_as_uint(rz);
        srec[pe] = rc;
    }
}

__global__ void dp_scat(const int* __restrict__ flagp,
                        const int* __restrict__ esrc, const int* __restrict__ edst,
                        const int* __restrict__ species,
                        const void* __restrict__ dist, const void* __restrict__ swt,
                        const void* __restrict__ vec,
                        const int* __restrict__ poffs, const int* __restrict__ rank,
                        uint4* __restrict__ srec, int* __restrict__ wstart)
{
    int i = blockIdx.x*256 + threadIdx.x;
    if (i <= NWAVES) wstart[i] = lb_poffs(poffs, i*EPW);
    if (*flagp) scat_body4<true >(esrc, edst, species, dist, swt, vec, poffs, rank, srec);
    else        scat_body4<false>(esrc, edst, species, dist, swt, vec, poffs, rank, srec);
}

// ---------------------------------------------------------------------------
// Fused MLP + aggregation + embedding. Node-decoupled group stream.
// UNCHANGED from the best-measured 154.3us version (control).
// ---------------------------------------------------------------------------
struct __align__(16) FusedShared {
    _Float16 WT[3][4096];   // [L][c*64 + (k ^ ((c&7)<<3))]
    float W1z[16*68];
    float W1r0[64];
    float bD[2][64];        // b2[pi(s)], b3[pi(s)]
    float Rl[8][128];       // per-wave R: A 0..63, B 64..127
    int nb[8][64];          // per-wave node-boundary cache poffs[n_lo+1+j]
};                          // 35840 B -> 4 blocks/CU

__global__ __launch_bounds__(512, 4) void dp_fused(
    const int* __restrict__ flagp,
    const void* __restrict__ W1, const void* __restrict__ b1,
    const void* __restrict__ W2, const void* __restrict__ b2,
    const void* __restrict__ W3, const void* __restrict__ b3,
    const void* __restrict__ W4, const void* __restrict__ b4,
    const int* __restrict__ poffs, const int* __restrict__ wstart,
    const uint4* __restrict__ srec,
    float* __restrict__ out)
{
    __shared__ FusedShared sh;
    const bool F32 = (*flagp != 0);
    const int tid = threadIdx.x;

    for (int i = tid; i < 4096; i += 512) {
        int k = i >> 6, c = i & 63;
        int kk = c*64 + (k ^ ((c & 7) << 3));
        int pc = dp_pi(c);
        if (F32) {
            sh.WT[0][kk] = (_Float16)ldv<true>(W2, k*64 + pc);
            sh.WT[1][kk] = (_Float16)ldv<true>(W3, k*64 + pc);
            sh.WT[2][kk] = (_Float16)ldv<true>(W4, k*64 + c);
        } else {
            sh.WT[0][kk] = (_Float16)ldv<false>(W2, k*64 + pc);
            sh.WT[1][kk] = (_Float16)ldv<false>(W3, k*64 + pc);
            sh.WT[2][kk] = (_Float16)ldv<false>(W4, k*64 + c);
        }
    }
    for (int i = tid; i < 16*64; i += 512) {
        int z = i >> 6, j = i & 63;
        sh.W1z[z*68 + j] = (F32 ? (ldv<true>(W1,(1+z)*64+j) + ldv<true>(b1,j))
                                : (ldv<false>(W1,(1+z)*64+j) + ldv<false>(b1,j)));
    }
    if (tid < 64) {
        int ps = dp_pi(tid);
        sh.W1r0[tid] = F32 ? ldv<true>(W1, tid) : ldv<false>(W1, tid);
        sh.bD[0][tid] = F32 ? ldv<true>(b2, ps) : ldv<false>(b2, ps);
        sh.bD[1][tid] = F32 ? ldv<true>(b3, ps) : ldv<false>(b3, ps);
    }

    const int lane = tid & 63;
    const int wid  = tid >> 6;
    const int col  = lane & 15;
    const int g    = lane >> 4;
    const int sw8  = (col & 7) << 3;

    float b4r[4];
    #pragma unroll
    for (int t = 0; t < 4; t++)
        b4r[t] = F32 ? ldv<true>(b4, 16*t + col) : ldv<false>(b4, 16*t + col);

    __syncthreads();

    float* RlA = sh.Rl[wid];
    float* RlB = sh.Rl[wid] + 64;
    int* nb = sh.nb[wid];

    const int w = blockIdx.x*8 + wid;
    const int n_lo = wstart[w];
    const int n_hi = wstart[w+1];
    const int nbn  = n_hi - n_lo;

    // cache node boundaries poffs[n_lo+1 .. n_hi] (<=64 typical; guarded)
    for (int j = lane; j < nbn && j < 64; j += 64) nb[j] = poffs[n_lo + 1 + j];

    if (n_lo >= n_hi) return;   // no nodes for this wave (no barriers below)

    auto nodeEnd = [&](int nd) -> int {
        int idx = nd - n_lo;
        return (idx < 64) ? nb[idx] : poffs[nd + 1];
    };

    const int pS = poffs[n_lo];
    const int pE = nodeEnd(n_hi - 1);

    int node = n_lo;
    int p1n  = nodeEnd(node);

    // GR accumulator packed along 'a': gr01[t] = (gr[a=0][t], gr[a=1][t])
    f32x2 gr01[4] = {{0,0},{0,0},{0,0},{0,0}};
    f32x2 gr23[4] = {{0,0},{0,0},{0,0},{0,0}};

    auto finishNode = [&](int nodeId) {
        float grf[4][4];
        #pragma unroll
        for (int t = 0; t < 4; t++) {
            grf[0][t] = gr01[t].x; grf[1][t] = gr01[t].y;
            grf[2][t] = gr23[t].x; grf[3][t] = gr23[t].y;
            gr01[t].x = 0.f; gr01[t].y = 0.f;
            gr23[t].x = 0.f; gr23[t].y = 0.f;
        }
        #pragma unroll
        for (int a = 0; a < 4; a++)
            #pragma unroll
            for (int t = 0; t < 4; t++) {
                float v = grf[a][t];
                v += __shfl_xor(v, 16);
                v += __shfl_xor(v, 32);
                grf[a][t] = v;
            }
        float gs0[4], gs1[4];
        #pragma unroll
        for (int a = 0; a < 4; a++) {
            gs0[a] = __shfl(grf[a][0], 2*g);
            gs1[a] = __shfl(grf[a][0], 2*g + 1);
        }
        #pragma unroll
        for (int t = 0; t < 4; t++) {
            float e0 = 0.f, e1 = 0.f;
            #pragma unroll
            for (int a = 0; a < 4; a++) {
                e0 = fmaf(grf[a][t], gs0[a], e0);
                e1 = fmaf(grf[a][t], gs1[a], e1);
            }
            float2 st; st.x = e0; st.y = e1;
            *(float2*)&out[(size_t)nodeId*512 + (16*t + col)*8 + 2*g] = st;
        }
    };

    // layer-4 + GR accumulate over rows [lo,hi) of the group (R masked).
    auto l4pass = [&](const half8& h0, const half8& h1, const float* Rlp,
                      int lo, int hi) {
        f32x4 Rm[4];
        #pragma unroll
        for (int j = 0; j < 4; j++) {
            int r = 4*g + j;
            float m = ((unsigned)(r - lo) < (unsigned)(hi - lo)) ? 1.0f : 0.0f;
            f32x4 Rj = *(const f32x4*)&Rlp[16*g + 4*j];
            Rm[j] = Rj * m;
        }
        #pragma unroll
        for (int t = 0; t < 4; t++) {
            const int wb = (16*t + col)*64;
            half8 w0 = *(const half8*)&sh.WT[2][wb + ((8*g) ^ sw8)];
            half8 w1 = *(const half8*)&sh.WT[2][wb + ((32 + 8*g) ^ sw8)];
            f32x4 c4 = {b4r[t], b4r[t], b4r[t], b4r[t]};
            f32x4 G = __builtin_amdgcn_mfma_f32_16x16x32_f16(h0, w0, c4, 0, 0, 0);
            G = __builtin_amdgcn_mfma_f32_16x16x32_f16(h1, w1, G, 0, 0, 0);
            #pragma unroll
            for (int j = 0; j < 4; j++) {
                f32x2 gs = {G[j], G[j]};
                gr01[t] = __builtin_elementwise_fma(gs, lo2(Rm[j]), gr01[t]);
                gr23[t] = __builtin_elementwise_fma(gs, hi2(Rm[j]), gr23[t]);
            }
        }
    };

    // GR stage for one 16-slot group at stream offset s: walk node segments.
    auto grPhase = [&](const half8& h0, const half8& h1, const float* Rlp, int s) {
        int segstart = s;
        while (true) {
            while (node < n_hi && p1n <= segstart) {
                finishNode(node);
                node++;
                if (node < n_hi) p1n = nodeEnd(node);
            }
            if (node >= n_hi || segstart >= s + 16) break;
            int segend = (p1n < s + 16) ? p1n : (s + 16);
            l4pass(h0, h1, Rlp, segstart - s, segend - s);
            segstart = segend;
        }
    };

    const int ngs = (pE - pS + 15) >> 4;   // stream groups for this wave

    int k = 0;
    // ================= paired stream groups =================
    for (; k + 2 <= ngs; k += 2) {
        const int sA = pS + 16*k;
        const int sB = sA + 16;
        uint4 rcA = srec[sA + col];          // A always fully valid
        int slotB = sB + col;
        const bool vB = slotB < pE;
        slotB = slotB < NEDGE-1 ? slotB : NEDGE-1;
        uint4 rcB = srec[slotB];
        if (!vB) { rcB.x = 0u; rcB.y = 0u; rcB.z = 0u; rcB.w = 0u; }
        const float sijA = __uint_as_float(rcA.x);
        const float sijB = __uint_as_float(rcB.x);
        const int zA = (int)(rcA.x & 15u);
        const int zB = (int)(rcB.x & 15u);
        if (g == 0) {
            *(uint4*)&RlA[col*4] = rcA;
            *(uint4*)&RlB[col*4] = rcB;
        }

        // ---- layer 1 both (packed-fp32 fma + packed silu -> f16 pairs)
        half8 h0A, h1A, h0B, h1B;
        {
            const float* wzA = &sh.W1z[zA*68];
            const float* wzB = &sh.W1z[zB*68];
            f32x4 r0 = *(const f32x4*)&sh.W1r0[8*g];
            f32x4 r1 = *(const f32x4*)&sh.W1r0[8*g + 4];
            f32x4 r2 = *(const f32x4*)&sh.W1r0[32 + 8*g];
            f32x4 r3 = *(const f32x4*)&sh.W1r0[32 + 8*g + 4];
            f32x4 a0 = *(const f32x4*)&wzA[8*g];
            f32x4 a1 = *(const f32x4*)&wzA[8*g + 4];
            f32x4 a2 = *(const f32x4*)&wzA[32 + 8*g];
            f32x4 a3 = *(const f32x4*)&wzA[32 + 8*g + 4];
            f32x4 c0 = *(const f32x4*)&wzB[8*g];
            f32x4 c1 = *(const f32x4*)&wzB[8*g + 4];
            f32x4 c2 = *(const f32x4*)&wzB[32 + 8*g];
            f32x4 c3 = *(const f32x4*)&wzB[32 + 8*g + 4];
            f32x2 sA2 = {sijA, sijA};
            f32x2 sB2 = {sijB, sijB};
            H8U u0A, u1A, u0B, u1B;
            u0A.u[0] = silu2_pk(__builtin_elementwise_fma(sA2, lo2(r0), lo2(a0)));
            u0A.u[1] = silu2_pk(__builtin_elementwise_fma(sA2, hi2(r0), hi2(a0)));
            u0A.u[2] = silu2_pk(__builtin_elementwise_fma(sA2, lo2(r1), lo2(a1)));
            u0A.u[3] = silu2_pk(__builtin_elementwise_fma(sA2, hi2(r1), hi2(a1)));
            u1A.u[0] = silu2_pk(__builtin_elementwise_fma(sA2, lo2(r2), lo2(a2)));
            u1A.u[1] = silu2_pk(__builtin_elementwise_fma(sA2, hi2(r2), hi2(a2)));
            u1A.u[2] = silu2_pk(__builtin_elementwise_fma(sA2, lo2(r3), lo2(a3)));
            u1A.u[3] = silu2_pk(__builtin_elementwise_fma(sA2, hi2(r3), hi2(a3)));
            u0B.u[0] = silu2_pk(__builtin_elementwise_fma(sB2, lo2(r0), lo2(c0)));
            u0B.u[1] = silu2_pk(__builtin_elementwise_fma(sB2, hi2(r0), hi2(c0)));
            u0B.u[2] = silu2_pk(__builtin_elementwise_fma(sB2, lo2(r1), lo2(c1)));
            u0B.u[3] = silu2_pk(__builtin_elementwise_fma(sB2, hi2(r1), hi2(c1)));
            u1B.u[0] = silu2_pk(__builtin_elementwise_fma(sB2, lo2(r2), lo2(c2)));
            u1B.u[1] = silu2_pk(__builtin_elementwise_fma(sB2, hi2(r2), hi2(c2)));
            u1B.u[2] = silu2_pk(__builtin_elementwise_fma(sB2, lo2(r3), lo2(c3)));
            u1B.u[3] = silu2_pk(__builtin_elementwise_fma(sB2, hi2(r3), hi2(c3)));
            h0A = u0A.h8; h1A = u1A.h8;
            h0B = u0B.h8; h1B = u1B.h8;
        }

        f32x4 accA[4], accB[4];

        // ---- layer 2 (shared weight/bias reads)
        #pragma unroll
        for (int t = 0; t < 4; t++) {
            const int wb = (16*t + col)*64;
            half8 w0 = *(const half8*)&sh.WT[0][wb + ((8*g) ^ sw8)];
            half8 w1 = *(const half8*)&sh.WT[0][wb + ((32 + 8*g) ^ sw8)];
            f32x4 cb = *(const f32x4*)&sh.bD[0][16*t + 4*g];
            f32x4 a = __builtin_amdgcn_mfma_f32_16x16x32_f16(w0, h0A, cb, 0, 0, 0);
            accA[t]  = __builtin_amdgcn_mfma_f32_16x16x32_f16(w1, h1A, a, 0, 0, 0);
            f32x4 b = __builtin_amdgcn_mfma_f32_16x16x32_f16(w0, h0B, cb, 0, 0, 0);
            accB[t]  = __builtin_amdgcn_mfma_f32_16x16x32_f16(w1, h1B, b, 0, 0, 0);
        }
        repack_silu(accA, h0A, h1A);
        repack_silu(accB, h0B, h1B);

        // ---- layer 3
        #pragma unroll
        for (int t = 0; t < 4; t++) {
            const int wb = (16*t + col)*64;
            half8 w0 = *(const half8*)&sh.WT[1][wb + ((8*g) ^ sw8)];
            half8 w1 = *(const half8*)&sh.WT[1][wb + ((32 + 8*g) ^ sw8)];
            f32x4 cb = *(const f32x4*)&sh.bD[1][16*t + 4*g];
            f32x4 a = __builtin_amdgcn_mfma_f32_16x16x32_f16(w0, h0A, cb, 0, 0, 0);
            accA[t]  = __builtin_amdgcn_mfma_f32_16x16x32_f16(w1, h1A, a, 0, 0, 0);
            f32x4 b = __builtin_amdgcn_mfma_f32_16x16x32_f16(w0, h0B, cb, 0, 0, 0);
            accB[t]  = __builtin_amdgcn_mfma_f32_16x16x32_f16(w1, h1B, b, 0, 0, 0);
        }
        repack_silu(accA, h0A, h1A);
        repack_silu(accB, h0B, h1B);

        // ---- layer 4 + GR, segmented by node boundaries
        grPhase(h0A, h1A, RlA, sA);
        grPhase(h0B, h1B, RlB, sB);
    }

    // ================= odd tail stream group =================
    if (k < ngs) {
        const int sA = pS + 16*k;
        int slot = sA + col;
        const bool v = slot < pE;
        slot = slot < NEDGE-1 ? slot : NEDGE-1;
        uint4 rc = srec[slot];
        if (!v) { rc.x = 0u; rc.y = 0u; rc.z = 0u; rc.w = 0u; }
        const float sij = __uint_as_float(rc.x);
        const int z = (int)(rc.x & 15u);
        if (g == 0) {
            *(uint4*)&RlA[col*4] = rc;
        }

        half8 h0, h1;
        {
            const float* wz = &sh.W1z[z*68];
            f32x4 a0 = *(const f32x4*)&wz[8*g];
            f32x4 a1 = *(const f32x4*)&wz[8*g + 4];
            f32x4 a2 = *(const f32x4*)&wz[32 + 8*g];
            f32x4 a3 = *(const f32x4*)&wz[32 + 8*g + 4];
            f32x4 r0 = *(const f32x4*)&sh.W1r0[8*g];
            f32x4 r1 = *(const f32x4*)&sh.W1r0[8*g + 4];
            f32x4 r2 = *(const f32x4*)&sh.W1r0[32 + 8*g];
            f32x4 r3 = *(const f32x4*)&sh.W1r0[32 + 8*g + 4];
            f32x2 s2 = {sij, sij};
            H8U u0, u1;
            u0.u[0] = silu2_pk(__builtin_elementwise_fma(s2, lo2(r0), lo2(a0)));
            u0.u[1] = silu2_pk(__builtin_elementwise_fma(s2, hi2(r0), hi2(a0)));
            u0.u[2] = silu2_pk(__builtin_elementwise_fma(s2, lo2(r1), lo2(a1)));
            u0.u[3] = silu2_pk(__builtin_elementwise_fma(s2, hi2(r1), hi2(a1)));
            u1.u[0] = silu2_pk(__builtin_elementwise_fma(s2, lo2(r2), lo2(a2)));
            u1.u[1] = silu2_pk(__builtin_elementwise_fma(s2, hi2(r2), hi2(a2)));
            u1.u[2] = silu2_pk(__builtin_elementwise_fma(s2, lo2(r3), lo2(a3)));
            u1.u[3] = silu2_pk(__builtin_elementwise_fma(s2, hi2(r3), hi2(a3)));
            h0 = u0.h8; h1 = u1.h8;
        }

        f32x4 acc[4];
        #pragma unroll
        for (int t = 0; t < 4; t++) {
            const int wb = (16*t + col)*64;
            half8 w0 = *(const half8*)&sh.WT[0][wb + ((8*g) ^ sw8)];
            half8 w1 = *(const half8*)&sh.WT[0][wb + ((32 + 8*g) ^ sw8)];
            f32x4 cb = *(const f32x4*)&sh.bD[0][16*t + 4*g];
            f32x4 a = __builtin_amdgcn_mfma_f32_16x16x32_f16(w0, h0, cb, 0, 0, 0);
            acc[t]  = __builtin_amdgcn_mfma_f32_16x16x32_f16(w1, h1, a, 0, 0, 0);
        }
        repack_silu(acc, h0, h1);

        #pragma unroll
        for (int t = 0; t < 4; t++) {
            const int wb = (16*t + col)*64;
            half8 w0 = *(const half8*)&sh.WT[1][wb + ((8*g) ^ sw8)];
            half8 w1 = *(const half8*)&sh.WT[1][wb + ((32 + 8*g) ^ sw8)];
            f32x4 cb = *(const f32x4*)&sh.bD[1][16*t + 4*g];
            f32x4 a = __builtin_amdgcn_mfma_f32_16x16x32_f16(w0, h0, cb, 0, 0, 0);
            acc[t]  = __builtin_amdgcn_mfma_f32_16x16x32_f16(w1, h1, a, 0, 0, 0);
        }
        repack_silu(acc, h0, h1);

        grPhase(h0, h1, RlA, sA);
    }

    // finish remaining nodes (last node + any trailing empty nodes)
    while (node < n_hi) {
        finishNode(node);
        node++;
    }
}

// ---------------------------------------------------------------------------
extern "C" void kernel_launch(void* const* d_in, const int* in_sizes, int n_in,
                              void* d_out, int out_size, void* d_ws, size_t ws_size,
                              hipStream_t stream)
{
    const int* species = (const int*)d_in[0];
    const int* esrc    = (const int*)d_in[1];
    const int* edst    = (const int*)d_in[2];
    const void* dist = d_in[3];
    const void* swt  = d_in[4];
    const void* vec  = d_in[5];
    const void* W1 = d_in[6];
    const void* b1 = d_in[7];
    const void* W2 = d_in[8];
    const void* b2 = d_in[9];
    const void* W3 = d_in[10];
    const void* b3 = d_in[11];
    const void* W4 = d_in[12];
    const void* b4 = d_in[13];
    float* out = (float*)d_out;

    char* base = (char*)d_ws;
    size_t off = 0;
    int* flag  = (int*)(base + off);    off += 256;
    uint4* srec = (uint4*)(base + off); off += (size_t)NEDGE*16;     // 25.6 MB dense
    int* counts = (int*)(base + off);   off += (size_t)NNODE*4;
    int* poffs  = (int*)(base + off);   off += (size_t)(NNODE+1)*4 + 12;
    int* rank   = (int*)(base + off);   off += (size_t)NEDGE*4;      // 6.4 MB
    int* wstart = (int*)(base + off);   off += (size_t)(NWAVES+1)*4 + 12;
    int* bsum   = (int*)(base + off);   off += 1024;
    int* bpre   = (int*)(base + off);   off += 1024;
    (void)ws_size; (void)in_sizes; (void)n_in; (void)out_size;

    (void)hipMemsetAsync(counts, 0, (size_t)NNODE*4, stream);

    dp_hist<<<NEDGE/256, 256, 0, stream>>>(esrc, counts, rank,
                                           (const unsigned int*)dist, flag);
    dp_s1<<<SCAN_BLOCKS, 256, 0, stream>>>(counts, bsum);
    dp_s2<<<1, 256, 0, stream>>>(bsum, bpre);
    dp_s3<<<SCAN_BLOCKS, 256, 0, stream>>>(counts, bpre, poffs);
    dp_scat<<<(NEDGE/4 + 255)/256, 256, 0, stream>>>(flag, esrc, edst, species,
                                           dist, swt, vec, poffs, rank, srec, wstart);
    dp_fused<<<NBLOCKS, 512, 0, stream>>>(flag, W1, b1, W2, b2, W3, b3, W4, b4,
                                          poffs, wstart, srec, out);
}

// Round 8
// 246.017 us; speedup vs baseline: 1.0835x; 1.0283x over previous
//
#include <hip/hip_runtime.h>

#define NNODE 50000
#define NEDGE 1600000
#define SCAN_BLOCKS 196   // ceil(50000/256)
#define NBLOCKS 1024      // 4 blocks/CU
#define NWAVES (NBLOCKS*8)
#define EPW 196           // ceil(NEDGE/NWAVES)

typedef __attribute__((ext_vector_type(8))) _Float16 half8;
typedef __attribute__((ext_vector_type(2))) __fp16 fp16x2;
typedef __attribute__((ext_vector_type(4))) float f32x4;
typedef __attribute__((ext_vector_type(2))) float f32x2;

union H2U { fp16x2 h; unsigned int u; };
union H8U { half8 h8; unsigned int u[4]; };

__device__ __forceinline__ float b2f(unsigned short u) {
    return __uint_as_float(((unsigned int)u) << 16);
}
__device__ __forceinline__ f32x2 lo2(f32x4 v) { f32x2 r; r.x = v[0]; r.y = v[1]; return r; }
__device__ __forceinline__ f32x2 hi2(f32x4 v) { f32x2 r; r.x = v[2]; r.y = v[3]; return r; }

// packed-pair silu -> packed f16 pair (v_pk_mul/add_f32 + 2x exp2/rcp + cvt_pkrtz)
__device__ __forceinline__ unsigned int silu2_pk(f32x2 x) {
    f32x2 u = x * (-1.44269504f);
    f32x2 e;
    e.x = __builtin_amdgcn_exp2f(u.x);
    e.y = __builtin_amdgcn_exp2f(u.y);
    f32x2 d = e + 1.0f;
    f32x2 r;
    r.x = __builtin_amdgcn_rcpf(d.x);
    r.y = __builtin_amdgcn_rcpf(d.y);
    f32x2 s = x * r;
    H2U h2; h2.h = __builtin_amdgcn_cvt_pkrtz(s.x, s.y);
    return h2.u;
}

// channel permutation folding the MFMA D-layout into the next layer's
// B-fragment layout (cols of W2/W3 only; repack restores true space).
__device__ __forceinline__ int dp_pi(int s) {
    return (((s >> 5) & 1) << 5) | (((s >> 2) & 3) << 3)
         | (((s >> 4) & 1) << 2) | (s & 3);
}
__device__ __forceinline__ void repack_silu(const f32x4 acc[4], half8& b0, half8& b1) {
    H8U u0, u1;
    u0.u[0] = silu2_pk(lo2(acc[0])); u0.u[1] = silu2_pk(hi2(acc[0]));
    u0.u[2] = silu2_pk(lo2(acc[1])); u0.u[3] = silu2_pk(hi2(acc[1]));
    u1.u[0] = silu2_pk(lo2(acc[2])); u1.u[1] = silu2_pk(hi2(acc[2]));
    u1.u[2] = silu2_pk(lo2(acc[3])); u1.u[3] = silu2_pk(hi2(acc[3]));
    b0 = u0.h8; b1 = u1.h8;
}

template<bool F32>
__device__ __forceinline__ float ldv(const void* p, int i) {
    return F32 ? ((const float*)p)[i] : b2f(((const unsigned short*)p)[i]);
}

__device__ __forceinline__ int lb_poffs(const int* __restrict__ poffs, int val) {
    int lo = 0, hi = NNODE;
    while (lo < hi) { int mid = (lo + hi) >> 1; if (poffs[mid] < val) lo = mid + 1; else hi = mid; }
    return lo;
}

// ---------------------------------------------------------------------------
// hist (+ input-dtype probe in block 0) + per-edge rank record.
// ---------------------------------------------------------------------------
__global__ void dp_hist(const int* __restrict__ esrc, int* __restrict__ counts,
                        int* __restrict__ rank,
                        const unsigned int* __restrict__ dw, int* __restrict__ flag) {
    if (blockIdx.x == 0 && threadIdx.x < 64) {
        const int lane = threadIdx.x;
        unsigned int w = dw[lane];
        unsigned int hb_ = (w >> 8) & 0xFF;
        bool bf16like = (hb_ == 0x3F) || (hb_ == 0x40);
        unsigned long long m = __ballot(bf16like);
        if (lane == 0) *flag = (__popcll(m) > 32) ? 0 : 1;
    }
    int i = blockIdx.x*256 + threadIdx.x;
    if (i < NEDGE) rank[i] = atomicAdd(&counts[esrc[i]], 1);
}

// s1: per-block unpadded sums
__global__ void dp_s1(const int* __restrict__ counts, int* __restrict__ bsum) {
    int i = blockIdx.x*256 + threadIdx.x;
    int v = (i < NNODE) ? counts[i] : 0;
    #pragma unroll
    for (int o = 32; o > 0; o >>= 1) v += __shfl_down(v, o);
    __shared__ int wsum[4];
    if ((threadIdx.x & 63) == 0) wsum[threadIdx.x >> 6] = v;
    __syncthreads();
    if (threadIdx.x == 0) bsum[blockIdx.x] = wsum[0] + wsum[1] + wsum[2] + wsum[3];
}

// s23: merged block-prefix (recomputed per block from bsum) + local scan.
// Removes the former 1-block s2 kernel and its launch/drain boundary.
__global__ void dp_s23(const int* __restrict__ counts, const int* __restrict__ bsum,
                       int* __restrict__ poffs) {
    __shared__ int sh[256];
    int t = threadIdx.x;
    // phase A: inclusive scan of bsum (196 entries) -> this block's excl prefix
    int vb = (t < SCAN_BLOCKS) ? bsum[t] : 0;
    sh[t] = vb;
    __syncthreads();
    for (int o = 1; o < 256; o <<= 1) {
        int x = (t >= o) ? sh[t - o] : 0;
        __syncthreads();
        sh[t] += x;
        __syncthreads();
    }
    const int bpre = (blockIdx.x > 0) ? sh[blockIdx.x - 1] : 0;
    __syncthreads();
    // phase B: local scan of this block's counts (original s3 body)
    int i = blockIdx.x*256 + t;
    int c = (i < NNODE) ? counts[i] : 0;
    sh[t] = c;
    __syncthreads();
    for (int o = 1; o < 256; o <<= 1) {
        int x = (t >= o) ? sh[t - o] : 0;
        __syncthreads();
        sh[t] += x;
        __syncthreads();
    }
    int excl = sh[t] - c + bpre;
    if (i < NNODE) poffs[i] = excl;
    if (i == NNODE-1) poffs[NNODE] = excl + c;
}

// ---------------------------------------------------------------------------
// Scatter + per-edge prep, atomic-free, DENSE positions (1 edge/thread,
// max TLP -- 4-edge batching measured slower). Also computes the per-wave
// node-range starts (wstart).
// ---------------------------------------------------------------------------
template<bool F32>
__device__ __forceinline__ void scat_body(
    const int* __restrict__ esrc, const int* __restrict__ edst,
    const int* __restrict__ species,
    const void* __restrict__ dist, const void* __restrict__ swt,
    const void* __restrict__ vec,
    const int* __restrict__ poffs, const int* __restrict__ rank,
    uint4* __restrict__ srec)
{
    int i = blockIdx.x*256 + threadIdx.x;
    if (i >= NEDGE) return;
    int pe = poffs[esrc[i]] + rank[i];
    float d  = ldv<F32>(dist, i);
    float sw = ldv<F32>(swt, i);
    float inv = 1.0f / d;
    float sij = sw * inv;
    float rx = sij * ldv<F32>(vec, 3*i+0) * inv;
    float ry = sij * ldv<F32>(vec, 3*i+1) * inv;
    float rz = sij * ldv<F32>(vec, 3*i+2) * inv;
    int z = species[edst[i]] & 15;
    uint4 rc;
    rc.x = (__float_as_uint(sij) & ~15u) | (unsigned)z;
    rc.y = __float_as_uint(rx);
    rc.z = __float_as_uint(ry);
    rc.w = __float_as_uint(rz);
    srec[pe] = rc;
}

__global__ void dp_scat(const int* __restrict__ flagp,
                        const int* __restrict__ esrc, const int* __restrict__ edst,
                        const int* __restrict__ species,
                        const void* __restrict__ dist, const void* __restrict__ swt,
                        const void* __restrict__ vec,
                        const int* __restrict__ poffs, const int* __restrict__ rank,
                        uint4* __restrict__ srec, int* __restrict__ wstart)
{
    int i = blockIdx.x*256 + threadIdx.x;
    if (i <= NWAVES) wstart[i] = lb_poffs(poffs, i*EPW);
    if (*flagp) scat_body<true >(esrc, edst, species, dist, swt, vec, poffs, rank, srec);
    else        scat_body<false>(esrc, edst, species, dist, swt, vec, poffs, rank, srec);
}

// ---------------------------------------------------------------------------
// Fused MLP + aggregation + embedding. Node-decoupled group stream.
// UNCHANGED from the best-measured 154.3us version (control).
// ---------------------------------------------------------------------------
struct __align__(16) FusedShared {
    _Float16 WT[3][4096];   // [L][c*64 + (k ^ ((c&7)<<3))]
    float W1z[16*68];
    float W1r0[64];
    float bD[2][64];        // b2[pi(s)], b3[pi(s)]
    float Rl[8][128];       // per-wave R: A 0..63, B 64..127
    int nb[8][64];          // per-wave node-boundary cache poffs[n_lo+1+j]
};                          // 35840 B -> 4 blocks/CU

__global__ __launch_bounds__(512, 4) void dp_fused(
    const int* __restrict__ flagp,
    const void* __restrict__ W1, const void* __restrict__ b1,
    const void* __restrict__ W2, const void* __restrict__ b2,
    const void* __restrict__ W3, const void* __restrict__ b3,
    const void* __restrict__ W4, const void* __restrict__ b4,
    const int* __restrict__ poffs, const int* __restrict__ wstart,
    const uint4* __restrict__ srec,
    float* __restrict__ out)
{
    __shared__ FusedShared sh;
    const bool F32 = (*flagp != 0);
    const int tid = threadIdx.x;

    for (int i = tid; i < 4096; i += 512) {
        int k = i >> 6, c = i & 63;
        int kk = c*64 + (k ^ ((c & 7) << 3));
        int pc = dp_pi(c);
        if (F32) {
            sh.WT[0][kk] = (_Float16)ldv<true>(W2, k*64 + pc);
            sh.WT[1][kk] = (_Float16)ldv<true>(W3, k*64 + pc);
            sh.WT[2][kk] = (_Float16)ldv<true>(W4, k*64 + c);
        } else {
            sh.WT[0][kk] = (_Float16)ldv<false>(W2, k*64 + pc);
            sh.WT[1][kk] = (_Float16)ldv<false>(W3, k*64 + pc);
            sh.WT[2][kk] = (_Float16)ldv<false>(W4, k*64 + c);
        }
    }
    for (int i = tid; i < 16*64; i += 512) {
        int z = i >> 6, j = i & 63;
        sh.W1z[z*68 + j] = (F32 ? (ldv<true>(W1,(1+z)*64+j) + ldv<true>(b1,j))
                                : (ldv<false>(W1,(1+z)*64+j) + ldv<false>(b1,j)));
    }
    if (tid < 64) {
        int ps = dp_pi(tid);
        sh.W1r0[tid] = F32 ? ldv<true>(W1, tid) : ldv<false>(W1, tid);
        sh.bD[0][tid] = F32 ? ldv<true>(b2, ps) : ldv<false>(b2, ps);
        sh.bD[1][tid] = F32 ? ldv<true>(b3, ps) : ldv<false>(b3, ps);
    }

    const int lane = tid & 63;
    const int wid  = tid >> 6;
    const int col  = lane & 15;
    const int g    = lane >> 4;
    const int sw8  = (col & 7) << 3;

    float b4r[4];
    #pragma unroll
    for (int t = 0; t < 4; t++)
        b4r[t] = F32 ? ldv<true>(b4, 16*t + col) : ldv<false>(b4, 16*t + col);

    __syncthreads();

    float* RlA = sh.Rl[wid];
    float* RlB = sh.Rl[wid] + 64;
    int* nb = sh.nb[wid];

    const int w = blockIdx.x*8 + wid;
    const int n_lo = wstart[w];
    const int n_hi = wstart[w+1];
    const int nbn  = n_hi - n_lo;

    // cache node boundaries poffs[n_lo+1 .. n_hi] (<=64 typical; guarded)
    for (int j = lane; j < nbn && j < 64; j += 64) nb[j] = poffs[n_lo + 1 + j];

    if (n_lo >= n_hi) return;   // no nodes for this wave (no barriers below)

    auto nodeEnd = [&](int nd) -> int {
        int idx = nd - n_lo;
        return (idx < 64) ? nb[idx] : poffs[nd + 1];
    };

    const int pS = poffs[n_lo];
    const int pE = nodeEnd(n_hi - 1);

    int node = n_lo;
    int p1n  = nodeEnd(node);

    // GR accumulator packed along 'a': gr01[t] = (gr[a=0][t], gr[a=1][t])
    f32x2 gr01[4] = {{0,0},{0,0},{0,0},{0,0}};
    f32x2 gr23[4] = {{0,0},{0,0},{0,0},{0,0}};

    auto finishNode = [&](int nodeId) {
        float grf[4][4];
        #pragma unroll
        for (int t = 0; t < 4; t++) {
            grf[0][t] = gr01[t].x; grf[1][t] = gr01[t].y;
            grf[2][t] = gr23[t].x; grf[3][t] = gr23[t].y;
            gr01[t].x = 0.f; gr01[t].y = 0.f;
            gr23[t].x = 0.f; gr23[t].y = 0.f;
        }
        #pragma unroll
        for (int a = 0; a < 4; a++)
            #pragma unroll
            for (int t = 0; t < 4; t++) {
                float v = grf[a][t];
                v += __shfl_xor(v, 16);
                v += __shfl_xor(v, 32);
                grf[a][t] = v;
            }
        float gs0[4], gs1[4];
        #pragma unroll
        for (int a = 0; a < 4; a++) {
            gs0[a] = __shfl(grf[a][0], 2*g);
            gs1[a] = __shfl(grf[a][0], 2*g + 1);
        }
        #pragma unroll
        for (int t = 0; t < 4; t++) {
            float e0 = 0.f, e1 = 0.f;
            #pragma unroll
            for (int a = 0; a < 4; a++) {
                e0 = fmaf(grf[a][t], gs0[a], e0);
                e1 = fmaf(grf[a][t], gs1[a], e1);
            }
            float2 st; st.x = e0; st.y = e1;
            *(float2*)&out[(size_t)nodeId*512 + (16*t + col)*8 + 2*g] = st;
        }
    };

    // layer-4 + GR accumulate over rows [lo,hi) of the group (R masked).
    auto l4pass = [&](const half8& h0, const half8& h1, const float* Rlp,
                      int lo, int hi) {
        f32x4 Rm[4];
        #pragma unroll
        for (int j = 0; j < 4; j++) {
            int r = 4*g + j;
            float m = ((unsigned)(r - lo) < (unsigned)(hi - lo)) ? 1.0f : 0.0f;
            f32x4 Rj = *(const f32x4*)&Rlp[16*g + 4*j];
            Rm[j] = Rj * m;
        }
        #pragma unroll
        for (int t = 0; t < 4; t++) {
            const int wb = (16*t + col)*64;
            half8 w0 = *(const half8*)&sh.WT[2][wb + ((8*g) ^ sw8)];
            half8 w1 = *(const half8*)&sh.WT[2][wb + ((32 + 8*g) ^ sw8)];
            f32x4 c4 = {b4r[t], b4r[t], b4r[t], b4r[t]};
            f32x4 G = __builtin_amdgcn_mfma_f32_16x16x32_f16(h0, w0, c4, 0, 0, 0);
            G = __builtin_amdgcn_mfma_f32_16x16x32_f16(h1, w1, G, 0, 0, 0);
            #pragma unroll
            for (int j = 0; j < 4; j++) {
                f32x2 gs = {G[j], G[j]};
                gr01[t] = __builtin_elementwise_fma(gs, lo2(Rm[j]), gr01[t]);
                gr23[t] = __builtin_elementwise_fma(gs, hi2(Rm[j]), gr23[t]);
            }
        }
    };

    // GR stage for one 16-slot group at stream offset s: walk node segments.
    auto grPhase = [&](const half8& h0, const half8& h1, const float* Rlp, int s) {
        int segstart = s;
        while (true) {
            while (node < n_hi && p1n <= segstart) {
                finishNode(node);
                node++;
                if (node < n_hi) p1n = nodeEnd(node);
            }
            if (node >= n_hi || segstart >= s + 16) break;
            int segend = (p1n < s + 16) ? p1n : (s + 16);
            l4pass(h0, h1, Rlp, segstart - s, segend - s);
            segstart = segend;
        }
    };

    const int ngs = (pE - pS + 15) >> 4;   // stream groups for this wave

    int k = 0;
    // ================= paired stream groups =================
    for (; k + 2 <= ngs; k += 2) {
        const int sA = pS + 16*k;
        const int sB = sA + 16;
        uint4 rcA = srec[sA + col];          // A always fully valid
        int slotB = sB + col;
        const bool vB = slotB < pE;
        slotB = slotB < NEDGE-1 ? slotB : NEDGE-1;
        uint4 rcB = srec[slotB];
        if (!vB) { rcB.x = 0u; rcB.y = 0u; rcB.z = 0u; rcB.w = 0u; }
        const float sijA = __uint_as_float(rcA.x);
        const float sijB = __uint_as_float(rcB.x);
        const int zA = (int)(rcA.x & 15u);
        const int zB = (int)(rcB.x & 15u);
        if (g == 0) {
            *(uint4*)&RlA[col*4] = rcA;
            *(uint4*)&RlB[col*4] = rcB;
        }

        // ---- layer 1 both (packed-fp32 fma + packed silu -> f16 pairs)
        half8 h0A, h1A, h0B, h1B;
        {
            const float* wzA = &sh.W1z[zA*68];
            const float* wzB = &sh.W1z[zB*68];
            f32x4 r0 = *(const f32x4*)&sh.W1r0[8*g];
            f32x4 r1 = *(const f32x4*)&sh.W1r0[8*g + 4];
            f32x4 r2 = *(const f32x4*)&sh.W1r0[32 + 8*g];
            f32x4 r3 = *(const f32x4*)&sh.W1r0[32 + 8*g + 4];
            f32x4 a0 = *(const f32x4*)&wzA[8*g];
            f32x4 a1 = *(const f32x4*)&wzA[8*g + 4];
            f32x4 a2 = *(const f32x4*)&wzA[32 + 8*g];
            f32x4 a3 = *(const f32x4*)&wzA[32 + 8*g + 4];
            f32x4 c0 = *(const f32x4*)&wzB[8*g];
            f32x4 c1 = *(const f32x4*)&wzB[8*g + 4];
            f32x4 c2 = *(const f32x4*)&wzB[32 + 8*g];
            f32x4 c3 = *(const f32x4*)&wzB[32 + 8*g + 4];
            f32x2 sA2 = {sijA, sijA};
            f32x2 sB2 = {sijB, sijB};
            H8U u0A, u1A, u0B, u1B;
            u0A.u[0] = silu2_pk(__builtin_elementwise_fma(sA2, lo2(r0), lo2(a0)));
            u0A.u[1] = silu2_pk(__builtin_elementwise_fma(sA2, hi2(r0), hi2(a0)));
            u0A.u[2] = silu2_pk(__builtin_elementwise_fma(sA2, lo2(r1), lo2(a1)));
            u0A.u[3] = silu2_pk(__builtin_elementwise_fma(sA2, hi2(r1), hi2(a1)));
            u1A.u[0] = silu2_pk(__builtin_elementwise_fma(sA2, lo2(r2), lo2(a2)));
            u1A.u[1] = silu2_pk(__builtin_elementwise_fma(sA2, hi2(r2), hi2(a2)));
            u1A.u[2] = silu2_pk(__builtin_elementwise_fma(sA2, lo2(r3), lo2(a3)));
            u1A.u[3] = silu2_pk(__builtin_elementwise_fma(sA2, hi2(r3), hi2(a3)));
            u0B.u[0] = silu2_pk(__builtin_elementwise_fma(sB2, lo2(r0), lo2(c0)));
            u0B.u[1] = silu2_pk(__builtin_elementwise_fma(sB2, hi2(r0), hi2(c0)));
            u0B.u[2] = silu2_pk(__builtin_elementwise_fma(sB2, lo2(r1), lo2(c1)));
            u0B.u[3] = silu2_pk(__builtin_elementwise_fma(sB2, hi2(r1), hi2(c1)));
            u1B.u[0] = silu2_pk(__builtin_elementwise_fma(sB2, lo2(r2), lo2(c2)));
            u1B.u[1] = silu2_pk(__builtin_elementwise_fma(sB2, hi2(r2), hi2(c2)));
            u1B.u[2] = silu2_pk(__builtin_elementwise_fma(sB2, lo2(r3), lo2(c3)));
            u1B.u[3] = silu2_pk(__builtin_elementwise_fma(sB2, hi2(r3), hi2(c3)));
            h0A = u0A.h8; h1A = u1A.h8;
            h0B = u0B.h8; h1B = u1B.h8;
        }

        f32x4 accA[4], accB[4];

        // ---- layer 2 (shared weight/bias reads)
        #pragma unroll
        for (int t = 0; t < 4; t++) {
            const int wb = (16*t + col)*64;
            half8 w0 = *(const half8*)&sh.WT[0][wb + ((8*g) ^ sw8)];
            half8 w1 = *(const half8*)&sh.WT[0][wb + ((32 + 8*g) ^ sw8)];
            f32x4 cb = *(const f32x4*)&sh.bD[0][16*t + 4*g];
            f32x4 a = __builtin_amdgcn_mfma_f32_16x16x32_f16(w0, h0A, cb, 0, 0, 0);
            accA[t]  = __builtin_amdgcn_mfma_f32_16x16x32_f16(w1, h1A, a, 0, 0, 0);
            f32x4 b = __builtin_amdgcn_mfma_f32_16x16x32_f16(w0, h0B, cb, 0, 0, 0);
            accB[t]  = __builtin_amdgcn_mfma_f32_16x16x32_f16(w1, h1B, b, 0, 0, 0);
        }
        repack_silu(accA, h0A, h1A);
        repack_silu(accB, h0B, h1B);

        // ---- layer 3
        #pragma unroll
        for (int t = 0; t < 4; t++) {
            const int wb = (16*t + col)*64;
            half8 w0 = *(const half8*)&sh.WT[1][wb + ((8*g) ^ sw8)];
            half8 w1 = *(const half8*)&sh.WT[1][wb + ((32 + 8*g) ^ sw8)];
            f32x4 cb = *(const f32x4*)&sh.bD[1][16*t + 4*g];
            f32x4 a = __builtin_amdgcn_mfma_f32_16x16x32_f16(w0, h0A, cb, 0, 0, 0);
            accA[t]  = __builtin_amdgcn_mfma_f32_16x16x32_f16(w1, h1A, a, 0, 0, 0);
            f32x4 b = __builtin_amdgcn_mfma_f32_16x16x32_f16(w0, h0B, cb, 0, 0, 0);
            accB[t]  = __builtin_amdgcn_mfma_f32_16x16x32_f16(w1, h1B, b, 0, 0, 0);
        }
        repack_silu(accA, h0A, h1A);
        repack_silu(accB, h0B, h1B);

        // ---- layer 4 + GR, segmented by node boundaries
        grPhase(h0A, h1A, RlA, sA);
        grPhase(h0B, h1B, RlB, sB);
    }

    // ================= odd tail stream group =================
    if (k < ngs) {
        const int sA = pS + 16*k;
        int slot = sA + col;
        const bool v = slot < pE;
        slot = slot < NEDGE-1 ? slot : NEDGE-1;
        uint4 rc = srec[slot];
        if (!v) { rc.x = 0u; rc.y = 0u; rc.z = 0u; rc.w = 0u; }
        const float sij = __uint_as_float(rc.x);
        const int z = (int)(rc.x & 15u);
        if (g == 0) {
            *(uint4*)&RlA[col*4] = rc;
        }

        half8 h0, h1;
        {
            const float* wz = &sh.W1z[z*68];
            f32x4 a0 = *(const f32x4*)&wz[8*g];
            f32x4 a1 = *(const f32x4*)&wz[8*g + 4];
            f32x4 a2 = *(const f32x4*)&wz[32 + 8*g];
            f32x4 a3 = *(const f32x4*)&wz[32 + 8*g + 4];
            f32x4 r0 = *(const f32x4*)&sh.W1r0[8*g];
            f32x4 r1 = *(const f32x4*)&sh.W1r0[8*g + 4];
            f32x4 r2 = *(const f32x4*)&sh.W1r0[32 + 8*g];
            f32x4 r3 = *(const f32x4*)&sh.W1r0[32 + 8*g + 4];
            f32x2 s2 = {sij, sij};
            H8U u0, u1;
            u0.u[0] = silu2_pk(__builtin_elementwise_fma(s2, lo2(r0), lo2(a0)));
            u0.u[1] = silu2_pk(__builtin_elementwise_fma(s2, hi2(r0), hi2(a0)));
            u0.u[2] = silu2_pk(__builtin_elementwise_fma(s2, lo2(r1), lo2(a1)));
            u0.u[3] = silu2_pk(__builtin_elementwise_fma(s2, hi2(r1), hi2(a1)));
            u1.u[0] = silu2_pk(__builtin_elementwise_fma(s2, lo2(r2), lo2(a2)));
            u1.u[1] = silu2_pk(__builtin_elementwise_fma(s2, hi2(r2), hi2(a2)));
            u1.u[2] = silu2_pk(__builtin_elementwise_fma(s2, lo2(r3), lo2(a3)));
            u1.u[3] = silu2_pk(__builtin_elementwise_fma(s2, hi2(r3), hi2(a3)));
            h0 = u0.h8; h1 = u1.h8;
        }

        f32x4 acc[4];
        #pragma unroll
        for (int t = 0; t < 4; t++) {
            const int wb = (16*t + col)*64;
            half8 w0 = *(const half8*)&sh.WT[0][wb + ((8*g) ^ sw8)];
            half8 w1 = *(const half8*)&sh.WT[0][wb + ((32 + 8*g) ^ sw8)];
            f32x4 cb = *(const f32x4*)&sh.bD[0][16*t + 4*g];
            f32x4 a = __builtin_amdgcn_mfma_f32_16x16x32_f16(w0, h0, cb, 0, 0, 0);
            acc[t]  = __builtin_amdgcn_mfma_f32_16x16x32_f16(w1, h1, a, 0, 0, 0);
        }
        repack_silu(acc, h0, h1);

        #pragma unroll
        for (int t = 0; t < 4; t++) {
            const int wb = (16*t + col)*64;
            half8 w0 = *(const half8*)&sh.WT[1][wb + ((8*g) ^ sw8)];
            half8 w1 = *(const half8*)&sh.WT[1][wb + ((32 + 8*g) ^ sw8)];
            f32x4 cb = *(const f32x4*)&sh.bD[1][16*t + 4*g];
            f32x4 a = __builtin_amdgcn_mfma_f32_16x16x32_f16(w0, h0, cb, 0, 0, 0);
            acc[t]  = __builtin_amdgcn_mfma_f32_16x16x32_f16(w1, h1, a, 0, 0, 0);
        }
        repack_silu(acc, h0, h1);

        grPhase(h0, h1, RlA, sA);
    }

    // finish remaining nodes (last node + any trailing empty nodes)
    while (node < n_hi) {
        finishNode(node);
        node++;
    }
}

// ---------------------------------------------------------------------------
extern "C" void kernel_launch(void* const* d_in, const int* in_sizes, int n_in,
                              void* d_out, int out_size, void* d_ws, size_t ws_size,
                              hipStream_t stream)
{
    const int* species = (const int*)d_in[0];
    const int* esrc    = (const int*)d_in[1];
    const int* edst    = (const int*)d_in[2];
    const void* dist = d_in[3];
    const void* swt  = d_in[4];
    const void* vec  = d_in[5];
    const void* W1 = d_in[6];
    const void* b1 = d_in[7];
    const void* W2 = d_in[8];
    const void* b2 = d_in[9];
    const void* W3 = d_in[10];
    const void* b3 = d_in[11];
    const void* W4 = d_in[12];
    const void* b4 = d_in[13];
    float* out = (float*)d_out;

    char* base = (char*)d_ws;
    size_t off = 0;
    int* flag  = (int*)(base + off);    off += 256;
    uint4* srec = (uint4*)(base + off); off += (size_t)NEDGE*16;     // 25.6 MB dense
    int* counts = (int*)(base + off);   off += (size_t)NNODE*4;
    int* poffs  = (int*)(base + off);   off += (size_t)(NNODE+1)*4 + 12;
    int* rank   = (int*)(base + off);   off += (size_t)NEDGE*4;      // 6.4 MB
    int* wstart = (int*)(base + off);   off += (size_t)(NWAVES+1)*4 + 12;
    int* bsum   = (int*)(base + off);   off += 1024;
    (void)ws_size; (void)in_sizes; (void)n_in; (void)out_size;

    (void)hipMemsetAsync(counts, 0, (size_t)NNODE*4, stream);

    dp_hist<<<NEDGE/256, 256, 0, stream>>>(esrc, counts, rank,
                                           (const unsigned int*)dist, flag);
    dp_s1<<<SCAN_BLOCKS, 256, 0, stream>>>(counts, bsum);
    dp_s23<<<SCAN_BLOCKS, 256, 0, stream>>>(counts, bsum, poffs);
    dp_scat<<<NEDGE/256, 256, 0, stream>>>(flag, esrc, edst, species,
                                           dist, swt, vec, poffs, rank, srec, wstart);
    dp_fused<<<NBLOCKS, 512, 0, stream>>>(flag, W1, b1, W2, b2, W3, b3, W4, b4,
                                          poffs, wstart, srec, out);
}

// Round 9
// 244.805 us; speedup vs baseline: 1.0889x; 1.0050x over previous
//
#include <hip/hip_runtime.h>

#define NNODE 50000
#define NEDGE 1600000
#define SCAN_BLOCKS 196   // ceil(50000/256)
#define NBLOCKS 1024      // 4 blocks/CU
#define NWAVES (NBLOCKS*8)
#define EPW 196           // ceil(NEDGE/NWAVES)

typedef __attribute__((ext_vector_type(8))) _Float16 half8;
typedef __attribute__((ext_vector_type(2))) __fp16 fp16x2;
typedef __attribute__((ext_vector_type(4))) float f32x4;
typedef __attribute__((ext_vector_type(2))) float f32x2;

union H2U { fp16x2 h; unsigned int u; };
union H8U { half8 h8; unsigned int u[4]; };

__device__ __forceinline__ float b2f(unsigned short u) {
    return __uint_as_float(((unsigned int)u) << 16);
}
__device__ __forceinline__ f32x2 lo2(f32x4 v) { f32x2 r; r.x = v[0]; r.y = v[1]; return r; }
__device__ __forceinline__ f32x2 hi2(f32x4 v) { f32x2 r; r.x = v[2]; r.y = v[3]; return r; }

// packed-pair silu -> packed f16 pair (v_pk_mul/add_f32 + 2x exp2/rcp + cvt_pkrtz)
__device__ __forceinline__ unsigned int silu2_pk(f32x2 x) {
    f32x2 u = x * (-1.44269504f);
    f32x2 e;
    e.x = __builtin_amdgcn_exp2f(u.x);
    e.y = __builtin_amdgcn_exp2f(u.y);
    f32x2 d = e + 1.0f;
    f32x2 r;
    r.x = __builtin_amdgcn_rcpf(d.x);
    r.y = __builtin_amdgcn_rcpf(d.y);
    f32x2 s = x * r;
    H2U h2; h2.h = __builtin_amdgcn_cvt_pkrtz(s.x, s.y);
    return h2.u;
}

// channel permutation folding the MFMA D-layout into the next layer's
// B-fragment layout (cols of W2/W3 only; repack restores true space).
__device__ __forceinline__ int dp_pi(int s) {
    return (((s >> 5) & 1) << 5) | (((s >> 2) & 3) << 3)
         | (((s >> 4) & 1) << 2) | (s & 3);
}
__device__ __forceinline__ void repack_silu(const f32x4 acc[4], half8& b0, half8& b1) {
    H8U u0, u1;
    u0.u[0] = silu2_pk(lo2(acc[0])); u0.u[1] = silu2_pk(hi2(acc[0]));
    u0.u[2] = silu2_pk(lo2(acc[1])); u0.u[3] = silu2_pk(hi2(acc[1]));
    u1.u[0] = silu2_pk(lo2(acc[2])); u1.u[1] = silu2_pk(hi2(acc[2]));
    u1.u[2] = silu2_pk(lo2(acc[3])); u1.u[3] = silu2_pk(hi2(acc[3]));
    b0 = u0.h8; b1 = u1.h8;
}

template<bool F32>
__device__ __forceinline__ float ldv(const void* p, int i) {
    return F32 ? ((const float*)p)[i] : b2f(((const unsigned short*)p)[i]);
}

__device__ __forceinline__ int lb_poffs(const int* __restrict__ poffs, int val) {
    int lo = 0, hi = NNODE;
    while (lo < hi) { int mid = (lo + hi) >> 1; if (poffs[mid] < val) lo = mid + 1; else hi = mid; }
    return lo;
}

// ---------------------------------------------------------------------------
// hist (+ input-dtype probe in block 0) + per-edge rank record.
// ---------------------------------------------------------------------------
__global__ void dp_hist(const int* __restrict__ esrc, int* __restrict__ counts,
                        int* __restrict__ rank,
                        const unsigned int* __restrict__ dw, int* __restrict__ flag) {
    if (blockIdx.x == 0 && threadIdx.x < 64) {
        const int lane = threadIdx.x;
        unsigned int w = dw[lane];
        unsigned int hb_ = (w >> 8) & 0xFF;
        bool bf16like = (hb_ == 0x3F) || (hb_ == 0x40);
        unsigned long long m = __ballot(bf16like);
        if (lane == 0) *flag = (__popcll(m) > 32) ? 0 : 1;
    }
    int i = blockIdx.x*256 + threadIdx.x;
    if (i < NEDGE) rank[i] = atomicAdd(&counts[esrc[i]], 1);
}

// s1: per-block unpadded sums
__global__ void dp_s1(const int* __restrict__ counts, int* __restrict__ bsum) {
    int i = blockIdx.x*256 + threadIdx.x;
    int v = (i < NNODE) ? counts[i] : 0;
    #pragma unroll
    for (int o = 32; o > 0; o >>= 1) v += __shfl_down(v, o);
    __shared__ int wsum[4];
    if ((threadIdx.x & 63) == 0) wsum[threadIdx.x >> 6] = v;
    __syncthreads();
    if (threadIdx.x == 0) bsum[blockIdx.x] = wsum[0] + wsum[1] + wsum[2] + wsum[3];
}

// s23: merged block-prefix (recomputed per block from bsum) + local scan.
__global__ void dp_s23(const int* __restrict__ counts, const int* __restrict__ bsum,
                       int* __restrict__ poffs) {
    __shared__ int sh[256];
    int t = threadIdx.x;
    // phase A: inclusive scan of bsum (196 entries) -> this block's excl prefix
    int vb = (t < SCAN_BLOCKS) ? bsum[t] : 0;
    sh[t] = vb;
    __syncthreads();
    for (int o = 1; o < 256; o <<= 1) {
        int x = (t >= o) ? sh[t - o] : 0;
        __syncthreads();
        sh[t] += x;
        __syncthreads();
    }
    const int bpre = (blockIdx.x > 0) ? sh[blockIdx.x - 1] : 0;
    __syncthreads();
    // phase B: local scan of this block's counts
    int i = blockIdx.x*256 + t;
    int c = (i < NNODE) ? counts[i] : 0;
    sh[t] = c;
    __syncthreads();
    for (int o = 1; o < 256; o <<= 1) {
        int x = (t >= o) ? sh[t - o] : 0;
        __syncthreads();
        sh[t] += x;
        __syncthreads();
    }
    int excl = sh[t] - c + bpre;
    if (i < NNODE) poffs[i] = excl;
    if (i == NNODE-1) poffs[NNODE] = excl + c;
}

// ---------------------------------------------------------------------------
// Scatter + per-edge prep, atomic-free, DENSE positions (1 edge/thread,
// max TLP). Also computes the per-wave node-range starts (wstart).
// ---------------------------------------------------------------------------
template<bool F32>
__device__ __forceinline__ void scat_body(
    const int* __restrict__ esrc, const int* __restrict__ edst,
    const int* __restrict__ species,
    const void* __restrict__ dist, const void* __restrict__ swt,
    const void* __restrict__ vec,
    const int* __restrict__ poffs, const int* __restrict__ rank,
    uint4* __restrict__ srec)
{
    int i = blockIdx.x*256 + threadIdx.x;
    if (i >= NEDGE) return;
    int pe = poffs[esrc[i]] + rank[i];
    float d  = ldv<F32>(dist, i);
    float sw = ldv<F32>(swt, i);
    float inv = 1.0f / d;
    float sij = sw * inv;
    float rx = sij * ldv<F32>(vec, 3*i+0) * inv;
    float ry = sij * ldv<F32>(vec, 3*i+1) * inv;
    float rz = sij * ldv<F32>(vec, 3*i+2) * inv;
    int z = species[edst[i]] & 15;
    uint4 rc;
    rc.x = (__float_as_uint(sij) & ~15u) | (unsigned)z;
    rc.y = __float_as_uint(rx);
    rc.z = __float_as_uint(ry);
    rc.w = __float_as_uint(rz);
    srec[pe] = rc;
}

__global__ void dp_scat(const int* __restrict__ flagp,
                        const int* __restrict__ esrc, const int* __restrict__ edst,
                        const int* __restrict__ species,
                        const void* __restrict__ dist, const void* __restrict__ swt,
                        const void* __restrict__ vec,
                        const int* __restrict__ poffs, const int* __restrict__ rank,
                        uint4* __restrict__ srec, int* __restrict__ wstart)
{
    int i = blockIdx.x*256 + threadIdx.x;
    if (i <= NWAVES) wstart[i] = lb_poffs(poffs, i*EPW);
    if (*flagp) scat_body<true >(esrc, edst, species, dist, swt, vec, poffs, rank, srec);
    else        scat_body<false>(esrc, edst, species, dist, swt, vec, poffs, rank, srec);
}

// ---------------------------------------------------------------------------
// Fused MLP + aggregation + embedding. Node-decoupled group stream.
// This revision: s_setprio(1) around the MFMA+ds_read clusters (T5) --
// independent waves at different phases, latency-bound -> priority lets a
// wave finish its LDS burst without interleave delay. Zero VGPR cost.
// ---------------------------------------------------------------------------
struct __align__(16) FusedShared {
    _Float16 WT[3][4096];   // [L][c*64 + (k ^ ((c&7)<<3))]
    float W1z[16*68];
    float W1r0[64];
    float bD[2][64];        // b2[pi(s)], b3[pi(s)]
    float Rl[8][128];       // per-wave R: A 0..63, B 64..127
    int nb[8][64];          // per-wave node-boundary cache poffs[n_lo+1+j]
};                          // 35840 B -> 4 blocks/CU

__global__ __launch_bounds__(512, 4) void dp_fused(
    const int* __restrict__ flagp,
    const void* __restrict__ W1, const void* __restrict__ b1,
    const void* __restrict__ W2, const void* __restrict__ b2,
    const void* __restrict__ W3, const void* __restrict__ b3,
    const void* __restrict__ W4, const void* __restrict__ b4,
    const int* __restrict__ poffs, const int* __restrict__ wstart,
    const uint4* __restrict__ srec,
    float* __restrict__ out)
{
    __shared__ FusedShared sh;
    const bool F32 = (*flagp != 0);
    const int tid = threadIdx.x;

    for (int i = tid; i < 4096; i += 512) {
        int k = i >> 6, c = i & 63;
        int kk = c*64 + (k ^ ((c & 7) << 3));
        int pc = dp_pi(c);
        if (F32) {
            sh.WT[0][kk] = (_Float16)ldv<true>(W2, k*64 + pc);
            sh.WT[1][kk] = (_Float16)ldv<true>(W3, k*64 + pc);
            sh.WT[2][kk] = (_Float16)ldv<true>(W4, k*64 + c);
        } else {
            sh.WT[0][kk] = (_Float16)ldv<false>(W2, k*64 + pc);
            sh.WT[1][kk] = (_Float16)ldv<false>(W3, k*64 + pc);
            sh.WT[2][kk] = (_Float16)ldv<false>(W4, k*64 + c);
        }
    }
    for (int i = tid; i < 16*64; i += 512) {
        int z = i >> 6, j = i & 63;
        sh.W1z[z*68 + j] = (F32 ? (ldv<true>(W1,(1+z)*64+j) + ldv<true>(b1,j))
                                : (ldv<false>(W1,(1+z)*64+j) + ldv<false>(b1,j)));
    }
    if (tid < 64) {
        int ps = dp_pi(tid);
        sh.W1r0[tid] = F32 ? ldv<true>(W1, tid) : ldv<false>(W1, tid);
        sh.bD[0][tid] = F32 ? ldv<true>(b2, ps) : ldv<false>(b2, ps);
        sh.bD[1][tid] = F32 ? ldv<true>(b3, ps) : ldv<false>(b3, ps);
    }

    const int lane = tid & 63;
    const int wid  = tid >> 6;
    const int col  = lane & 15;
    const int g    = lane >> 4;
    const int sw8  = (col & 7) << 3;

    float b4r[4];
    #pragma unroll
    for (int t = 0; t < 4; t++)
        b4r[t] = F32 ? ldv<true>(b4, 16*t + col) : ldv<false>(b4, 16*t + col);

    __syncthreads();

    float* RlA = sh.Rl[wid];
    float* RlB = sh.Rl[wid] + 64;
    int* nb = sh.nb[wid];

    const int w = blockIdx.x*8 + wid;
    const int n_lo = wstart[w];
    const int n_hi = wstart[w+1];
    const int nbn  = n_hi - n_lo;

    // cache node boundaries poffs[n_lo+1 .. n_hi] (<=64 typical; guarded)
    for (int j = lane; j < nbn && j < 64; j += 64) nb[j] = poffs[n_lo + 1 + j];

    if (n_lo >= n_hi) return;   // no nodes for this wave (no barriers below)

    auto nodeEnd = [&](int nd) -> int {
        int idx = nd - n_lo;
        return (idx < 64) ? nb[idx] : poffs[nd + 1];
    };

    const int pS = poffs[n_lo];
    const int pE = nodeEnd(n_hi - 1);

    int node = n_lo;
    int p1n  = nodeEnd(node);

    // GR accumulator packed along 'a': gr01[t] = (gr[a=0][t], gr[a=1][t])
    f32x2 gr01[4] = {{0,0},{0,0},{0,0},{0,0}};
    f32x2 gr23[4] = {{0,0},{0,0},{0,0},{0,0}};

    auto finishNode = [&](int nodeId) {
        float grf[4][4];
        #pragma unroll
        for (int t = 0; t < 4; t++) {
            grf[0][t] = gr01[t].x; grf[1][t] = gr01[t].y;
            grf[2][t] = gr23[t].x; grf[3][t] = gr23[t].y;
            gr01[t].x = 0.f; gr01[t].y = 0.f;
            gr23[t].x = 0.f; gr23[t].y = 0.f;
        }
        #pragma unroll
        for (int a = 0; a < 4; a++)
            #pragma unroll
            for (int t = 0; t < 4; t++) {
                float v = grf[a][t];
                v += __shfl_xor(v, 16);
                v += __shfl_xor(v, 32);
                grf[a][t] = v;
            }
        float gs0[4], gs1[4];
        #pragma unroll
        for (int a = 0; a < 4; a++) {
            gs0[a] = __shfl(grf[a][0], 2*g);
            gs1[a] = __shfl(grf[a][0], 2*g + 1);
        }
        #pragma unroll
        for (int t = 0; t < 4; t++) {
            float e0 = 0.f, e1 = 0.f;
            #pragma unroll
            for (int a = 0; a < 4; a++) {
                e0 = fmaf(grf[a][t], gs0[a], e0);
                e1 = fmaf(grf[a][t], gs1[a], e1);
            }
            float2 st; st.x = e0; st.y = e1;
            *(float2*)&out[(size_t)nodeId*512 + (16*t + col)*8 + 2*g] = st;
        }
    };

    // layer-4 + GR accumulate over rows [lo,hi) of the group (R masked).
    auto l4pass = [&](const half8& h0, const half8& h1, const float* Rlp,
                      int lo, int hi) {
        f32x4 Rm[4];
        #pragma unroll
        for (int j = 0; j < 4; j++) {
            int r = 4*g + j;
            float m = ((unsigned)(r - lo) < (unsigned)(hi - lo)) ? 1.0f : 0.0f;
            f32x4 Rj = *(const f32x4*)&Rlp[16*g + 4*j];
            Rm[j] = Rj * m;
        }
        __builtin_amdgcn_s_setprio(1);
        f32x4 G4[4];
        #pragma unroll
        for (int t = 0; t < 4; t++) {
            const int wb = (16*t + col)*64;
            half8 w0 = *(const half8*)&sh.WT[2][wb + ((8*g) ^ sw8)];
            half8 w1 = *(const half8*)&sh.WT[2][wb + ((32 + 8*g) ^ sw8)];
            f32x4 c4 = {b4r[t], b4r[t], b4r[t], b4r[t]};
            f32x4 G = __builtin_amdgcn_mfma_f32_16x16x32_f16(h0, w0, c4, 0, 0, 0);
            G4[t] = __builtin_amdgcn_mfma_f32_16x16x32_f16(h1, w1, G, 0, 0, 0);
        }
        __builtin_amdgcn_s_setprio(0);
        #pragma unroll
        for (int t = 0; t < 4; t++) {
            #pragma unroll
            for (int j = 0; j < 4; j++) {
                f32x2 gs = {G4[t][j], G4[t][j]};
                gr01[t] = __builtin_elementwise_fma(gs, lo2(Rm[j]), gr01[t]);
                gr23[t] = __builtin_elementwise_fma(gs, hi2(Rm[j]), gr23[t]);
            }
        }
    };

    // GR stage for one 16-slot group at stream offset s: walk node segments.
    auto grPhase = [&](const half8& h0, const half8& h1, const float* Rlp, int s) {
        int segstart = s;
        while (true) {
            while (node < n_hi && p1n <= segstart) {
                finishNode(node);
                node++;
                if (node < n_hi) p1n = nodeEnd(node);
            }
            if (node >= n_hi || segstart >= s + 16) break;
            int segend = (p1n < s + 16) ? p1n : (s + 16);
            l4pass(h0, h1, Rlp, segstart - s, segend - s);
            segstart = segend;
        }
    };

    const int ngs = (pE - pS + 15) >> 4;   // stream groups for this wave

    int k = 0;
    // ================= paired stream groups =================
    for (; k + 2 <= ngs; k += 2) {
        const int sA = pS + 16*k;
        const int sB = sA + 16;
        uint4 rcA = srec[sA + col];          // A always fully valid
        int slotB = sB + col;
        const bool vB = slotB < pE;
        slotB = slotB < NEDGE-1 ? slotB : NEDGE-1;
        uint4 rcB = srec[slotB];
        if (!vB) { rcB.x = 0u; rcB.y = 0u; rcB.z = 0u; rcB.w = 0u; }
        const float sijA = __uint_as_float(rcA.x);
        const float sijB = __uint_as_float(rcB.x);
        const int zA = (int)(rcA.x & 15u);
        const int zB = (int)(rcB.x & 15u);
        if (g == 0) {
            *(uint4*)&RlA[col*4] = rcA;
            *(uint4*)&RlB[col*4] = rcB;
        }

        // ---- layer 1 both (packed-fp32 fma + packed silu -> f16 pairs)
        half8 h0A, h1A, h0B, h1B;
        {
            const float* wzA = &sh.W1z[zA*68];
            const float* wzB = &sh.W1z[zB*68];
            f32x4 r0 = *(const f32x4*)&sh.W1r0[8*g];
            f32x4 r1 = *(const f32x4*)&sh.W1r0[8*g + 4];
            f32x4 r2 = *(const f32x4*)&sh.W1r0[32 + 8*g];
            f32x4 r3 = *(const f32x4*)&sh.W1r0[32 + 8*g + 4];
            f32x4 a0 = *(const f32x4*)&wzA[8*g];
            f32x4 a1 = *(const f32x4*)&wzA[8*g + 4];
            f32x4 a2 = *(const f32x4*)&wzA[32 + 8*g];
            f32x4 a3 = *(const f32x4*)&wzA[32 + 8*g + 4];
            f32x4 c0 = *(const f32x4*)&wzB[8*g];
            f32x4 c1 = *(const f32x4*)&wzB[8*g + 4];
            f32x4 c2 = *(const f32x4*)&wzB[32 + 8*g];
            f32x4 c3 = *(const f32x4*)&wzB[32 + 8*g + 4];
            f32x2 sA2 = {sijA, sijA};
            f32x2 sB2 = {sijB, sijB};
            H8U u0A, u1A, u0B, u1B;
            u0A.u[0] = silu2_pk(__builtin_elementwise_fma(sA2, lo2(r0), lo2(a0)));
            u0A.u[1] = silu2_pk(__builtin_elementwise_fma(sA2, hi2(r0), hi2(a0)));
            u0A.u[2] = silu2_pk(__builtin_elementwise_fma(sA2, lo2(r1), lo2(a1)));
            u0A.u[3] = silu2_pk(__builtin_elementwise_fma(sA2, hi2(r1), hi2(a1)));
            u1A.u[0] = silu2_pk(__builtin_elementwise_fma(sA2, lo2(r2), lo2(a2)));
            u1A.u[1] = silu2_pk(__builtin_elementwise_fma(sA2, hi2(r2), hi2(a2)));
            u1A.u[2] = silu2_pk(__builtin_elementwise_fma(sA2, lo2(r3), lo2(a3)));
            u1A.u[3] = silu2_pk(__builtin_elementwise_fma(sA2, hi2(r3), hi2(a3)));
            u0B.u[0] = silu2_pk(__builtin_elementwise_fma(sB2, lo2(r0), lo2(c0)));
            u0B.u[1] = silu2_pk(__builtin_elementwise_fma(sB2, hi2(r0), hi2(c0)));
            u0B.u[2] = silu2_pk(__builtin_elementwise_fma(sB2, lo2(r1), lo2(c1)));
            u0B.u[3] = silu2_pk(__builtin_elementwise_fma(sB2, hi2(r1), hi2(c1)));
            u1B.u[0] = silu2_pk(__builtin_elementwise_fma(sB2, lo2(r2), lo2(c2)));
            u1B.u[1] = silu2_pk(__builtin_elementwise_fma(sB2, hi2(r2), hi2(c2)));
            u1B.u[2] = silu2_pk(__builtin_elementwise_fma(sB2, lo2(r3), lo2(c3)));
            u1B.u[3] = silu2_pk(__builtin_elementwise_fma(sB2, hi2(r3), hi2(c3)));
            h0A = u0A.h8; h1A = u1A.h8;
            h0B = u0B.h8; h1B = u1B.h8;
        }

        f32x4 accA[4], accB[4];

        // ---- layer 2 (shared weight/bias reads)
        __builtin_amdgcn_s_setprio(1);
        #pragma unroll
        for (int t = 0; t < 4; t++) {
            const int wb = (16*t + col)*64;
            half8 w0 = *(const half8*)&sh.WT[0][wb + ((8*g) ^ sw8)];
            half8 w1 = *(const half8*)&sh.WT[0][wb + ((32 + 8*g) ^ sw8)];
            f32x4 cb = *(const f32x4*)&sh.bD[0][16*t + 4*g];
            f32x4 a = __builtin_amdgcn_mfma_f32_16x16x32_f16(w0, h0A, cb, 0, 0, 0);
            accA[t]  = __builtin_amdgcn_mfma_f32_16x16x32_f16(w1, h1A, a, 0, 0, 0);
            f32x4 b = __builtin_amdgcn_mfma_f32_16x16x32_f16(w0, h0B, cb, 0, 0, 0);
            accB[t]  = __builtin_amdgcn_mfma_f32_16x16x32_f16(w1, h1B, b, 0, 0, 0);
        }
        __builtin_amdgcn_s_setprio(0);
        repack_silu(accA, h0A, h1A);
        repack_silu(accB, h0B, h1B);

        // ---- layer 3
        __builtin_amdgcn_s_setprio(1);
        #pragma unroll
        for (int t = 0; t < 4; t++) {
            const int wb = (16*t + col)*64;
            half8 w0 = *(const half8*)&sh.WT[1][wb + ((8*g) ^ sw8)];
            half8 w1 = *(const half8*)&sh.WT[1][wb + ((32 + 8*g) ^ sw8)];
            f32x4 cb = *(const f32x4*)&sh.bD[1][16*t + 4*g];
            f32x4 a = __builtin_amdgcn_mfma_f32_16x16x32_f16(w0, h0A, cb, 0, 0, 0);
            accA[t]  = __builtin_amdgcn_mfma_f32_16x16x32_f16(w1, h1A, a, 0, 0, 0);
            f32x4 b = __builtin_amdgcn_mfma_f32_16x16x32_f16(w0, h0B, cb, 0, 0, 0);
            accB[t]  = __builtin_amdgcn_mfma_f32_16x16x32_f16(w1, h1B, b, 0, 0, 0);
        }
        __builtin_amdgcn_s_setprio(0);
        repack_silu(accA, h0A, h1A);
        repack_silu(accB, h0B, h1B);

        // ---- layer 4 + GR, segmented by node boundaries
        grPhase(h0A, h1A, RlA, sA);
        grPhase(h0B, h1B, RlB, sB);
    }

    // ================= odd tail stream group =================
    if (k < ngs) {
        const int sA = pS + 16*k;
        int slot = sA + col;
        const bool v = slot < pE;
        slot = slot < NEDGE-1 ? slot : NEDGE-1;
        uint4 rc = srec[slot];
        if (!v) { rc.x = 0u; rc.y = 0u; rc.z = 0u; rc.w = 0u; }
        const float sij = __uint_as_float(rc.x);
        const int z = (int)(rc.x & 15u);
        if (g == 0) {
            *(uint4*)&RlA[col*4] = rc;
        }

        half8 h0, h1;
        {
            const float* wz = &sh.W1z[z*68];
            f32x4 a0 = *(const f32x4*)&wz[8*g];
            f32x4 a1 = *(const f32x4*)&wz[8*g + 4];
            f32x4 a2 = *(const f32x4*)&wz[32 + 8*g];
            f32x4 a3 = *(const f32x4*)&wz[32 + 8*g + 4];
            f32x4 r0 = *(const f32x4*)&sh.W1r0[8*g];
            f32x4 r1 = *(const f32x4*)&sh.W1r0[8*g + 4];
            f32x4 r2 = *(const f32x4*)&sh.W1r0[32 + 8*g];
            f32x4 r3 = *(const f32x4*)&sh.W1r0[32 + 8*g + 4];
            f32x2 s2 = {sij, sij};
            H8U u0, u1;
            u0.u[0] = silu2_pk(__builtin_elementwise_fma(s2, lo2(r0), lo2(a0)));
            u0.u[1] = silu2_pk(__builtin_elementwise_fma(s2, hi2(r0), hi2(a0)));
            u0.u[2] = silu2_pk(__builtin_elementwise_fma(s2, lo2(r1), lo2(a1)));
            u0.u[3] = silu2_pk(__builtin_elementwise_fma(s2, hi2(r1), hi2(a1)));
            u1.u[0] = silu2_pk(__builtin_elementwise_fma(s2, lo2(r2), lo2(a2)));
            u1.u[1] = silu2_pk(__builtin_elementwise_fma(s2, hi2(r2), hi2(a2)));
            u1.u[2] = silu2_pk(__builtin_elementwise_fma(s2, lo2(r3), lo2(a3)));
            u1.u[3] = silu2_pk(__builtin_elementwise_fma(s2, hi2(r3), hi2(a3)));
            h0 = u0.h8; h1 = u1.h8;
        }

        f32x4 acc[4];
        __builtin_amdgcn_s_setprio(1);
        #pragma unroll
        for (int t = 0; t < 4; t++) {
            const int wb = (16*t + col)*64;
            half8 w0 = *(const half8*)&sh.WT[0][wb + ((8*g) ^ sw8)];
            half8 w1 = *(const half8*)&sh.WT[0][wb + ((32 + 8*g) ^ sw8)];
            f32x4 cb = *(const f32x4*)&sh.bD[0][16*t + 4*g];
            f32x4 a = __builtin_amdgcn_mfma_f32_16x16x32_f16(w0, h0, cb, 0, 0, 0);
            acc[t]  = __builtin_amdgcn_mfma_f32_16x16x32_f16(w1, h1, a, 0, 0, 0);
        }
        __builtin_amdgcn_s_setprio(0);
        repack_silu(acc, h0, h1);

        __builtin_amdgcn_s_setprio(1);
        #pragma unroll
        for (int t = 0; t < 4; t++) {
            const int wb = (16*t + col)*64;
            half8 w0 = *(const half8*)&sh.WT[1][wb + ((8*g) ^ sw8)];
            half8 w1 = *(const half8*)&sh.WT[1][wb + ((32 + 8*g) ^ sw8)];
            f32x4 cb = *(const f32x4*)&sh.bD[1][16*t + 4*g];
            f32x4 a = __builtin_amdgcn_mfma_f32_16x16x32_f16(w0, h0, cb, 0, 0, 0);
            acc[t]  = __builtin_amdgcn_mfma_f32_16x16x32_f16(w1, h1, a, 0, 0, 0);
        }
        __builtin_amdgcn_s_setprio(0);
        repack_silu(acc, h0, h1);

        grPhase(h0, h1, RlA, sA);
    }

    // finish remaining nodes (last node + any trailing empty nodes)
    while (node < n_hi) {
        finishNode(node);
        node++;
    }
}

// ---------------------------------------------------------------------------
extern "C" void kernel_launch(void* const* d_in, const int* in_sizes, int n_in,
                              void* d_out, int out_size, void* d_ws, size_t ws_size,
                              hipStream_t stream)
{
    const int* species = (const int*)d_in[0];
    const int* esrc    = (const int*)d_in[1];
    const int* edst    = (const int*)d_in[2];
    const void* dist = d_in[3];
    const void* swt  = d_in[4];
    const void* vec  = d_in[5];
    const void* W1 = d_in[6];
    const void* b1 = d_in[7];
    const void* W2 = d_in[8];
    const void* b2 = d_in[9];
    const void* W3 = d_in[10];
    const void* b3 = d_in[11];
    const void* W4 = d_in[12];
    const void* b4 = d_in[13];
    float* out = (float*)d_out;

    char* base = (char*)d_ws;
    size_t off = 0;
    int* flag  = (int*)(base + off);    off += 256;
    uint4* srec = (uint4*)(base + off); off += (size_t)NEDGE*16;     // 25.6 MB dense
    int* counts = (int*)(base + off);   off += (size_t)NNODE*4;
    int* poffs  = (int*)(base + off);   off += (size_t)(NNODE+1)*4 + 12;
    int* rank   = (int*)(base + off);   off += (size_t)NEDGE*4;      // 6.4 MB
    int* wstart = (int*)(base + off);   off += (size_t)(NWAVES+1)*4 + 12;
    int* bsum   = (int*)(base + off);   off += 1024;
    (void)ws_size; (void)in_sizes; (void)n_in; (void)out_size;

    (void)hipMemsetAsync(counts, 0, (size_t)NNODE*4, stream);

    dp_hist<<<NEDGE/256, 256, 0, stream>>>(esrc, counts, rank,
                                           (const unsigned int*)dist, flag);
    dp_s1<<<SCAN_BLOCKS, 256, 0, stream>>>(counts, bsum);
    dp_s23<<<SCAN_BLOCKS, 256, 0, stream>>>(counts, bsum, poffs);
    dp_scat<<<NEDGE/256, 256, 0, stream>>>(flag, esrc, edst, species,
                                           dist, swt, vec, poffs, rank, srec, wstart);
    dp_fused<<<NBLOCKS, 512, 0, stream>>>(flag, W1, b1, W2, b2, W3, b3, W4, b4,
                                          poffs, wstart, srec, out);
}